// Round 6
// baseline (1345.289 us; speedup 1.0000x reference)
//
#include <hip/hip_runtime.h>
#include <hip/hip_bf16.h>

#define N_NODES 100000
#define N_EDGES 1600000

#define NBKT 782                 // ceil(N_NODES / 128)
#define BKT_CHUNK 13334          // ceil(N_EDGES / 120)
#define SCAT_BLOCKS 120
#define LP 72                    // padded LDS row length in shorts (64 + 8)

typedef __attribute__((ext_vector_type(8))) short short8v;
typedef __attribute__((ext_vector_type(4))) float float4v;

__device__ __forceinline__ unsigned short f2bf(float f) {
    unsigned int u = __float_as_uint(f);
    u = (u + 0x7FFFu + ((u >> 16) & 1u)) >> 16;   // RTNE
    return (unsigned short)u;
}
__device__ __forceinline__ float bf2f(unsigned short b) {
    return __uint_as_float((unsigned int)b << 16);
}

// ---------------- CSR build via 2-level bucket counting sort ----------------

__global__ __launch_bounds__(256) void bkt_count_kernel(const int* __restrict__ ei, int* __restrict__ bucket_cnt) {
    __shared__ int h[NBKT];
    int tid = threadIdx.x;
    for (int i = tid; i < NBKT; i += 256) h[i] = 0;
    __syncthreads();
    int start = blockIdx.x * BKT_CHUNK;
    int end = start + BKT_CHUNK; if (end > N_EDGES) end = N_EDGES;
    for (int i = start + tid; i < end; i += 256) {
        int d = ei[N_EDGES + i];
        atomicAdd(&h[d >> 7], 1);
    }
    __syncthreads();
    for (int i = tid; i < NBKT; i += 256) {
        int c = h[i];
        if (c) atomicAdd(&bucket_cnt[i], c);
    }
}

__global__ __launch_bounds__(256) void bkt_scan_kernel(const int* __restrict__ bucket_cnt,
                                                       int* __restrict__ bucket_off, int* __restrict__ cursor) {
    __shared__ int ps[256];
    int tid = threadIdx.x;
    int base = tid * 4;
    int v[4];
    int s = 0;
    #pragma unroll
    for (int i = 0; i < 4; i++) {
        v[i] = (base + i < NBKT) ? bucket_cnt[base + i] : 0;
        s += v[i];
    }
    ps[tid] = s;
    __syncthreads();
    for (int off = 1; off < 256; off <<= 1) {
        int y = 0;
        if (tid >= off) y = ps[tid - off];
        __syncthreads();
        if (tid >= off) ps[tid] += y;
        __syncthreads();
    }
    int run = ps[tid] - s;   // exclusive
    #pragma unroll
    for (int i = 0; i < 4; i++) {
        if (base + i < NBKT) { bucket_off[base + i] = run; cursor[base + i] = run; }
        run += v[i];
    }
    if (tid == 0) bucket_off[NBKT] = N_EDGES;
}

__global__ __launch_bounds__(256) void bkt_scatter_kernel(const int* __restrict__ ei, int* __restrict__ cursor,
                                                          int2* __restrict__ pairs) {
    __shared__ int h[NBKT];
    __shared__ int basearr[NBKT];
    int tid = threadIdx.x;
    for (int i = tid; i < NBKT; i += 256) h[i] = 0;
    __syncthreads();
    int start = blockIdx.x * BKT_CHUNK;
    int end = start + BKT_CHUNK; if (end > N_EDGES) end = N_EDGES;
    for (int i = start + tid; i < end; i += 256) {
        int d = ei[N_EDGES + i];
        atomicAdd(&h[d >> 7], 1);
    }
    __syncthreads();
    for (int b = tid; b < NBKT; b += 256) {
        int c = h[b];
        basearr[b] = c ? atomicAdd(&cursor[b], c) : 0;
        h[b] = 0;
    }
    __syncthreads();
    for (int i = start + tid; i < end; i += 256) {
        int s = ei[i];
        int d = ei[N_EDGES + i];
        int bkt = d >> 7;
        int pos = basearr[bkt] + atomicAdd(&h[bkt], 1);
        pairs[pos] = make_int2(s, d);
    }
}

__global__ __launch_bounds__(256) void bkt_deg_kernel(const int2* __restrict__ pairs, const int* __restrict__ bucket_off,
                                                      int* __restrict__ deg) {
    __shared__ int c[128];
    int tid = threadIdx.x;
    if (tid < 128) c[tid] = 0;
    __syncthreads();
    int s0 = bucket_off[blockIdx.x], s1 = bucket_off[blockIdx.x + 1];
    for (int i = s0 + tid; i < s1; i += 256) {
        int d = pairs[i].y;
        atomicAdd(&c[d & 127], 1);
    }
    __syncthreads();
    int node = blockIdx.x * 128 + tid;
    if (tid < 128 && node < N_NODES) deg[node] = c[tid];
}

__global__ __launch_bounds__(256) void bkt_fill_kernel(const int2* __restrict__ pairs, const int* __restrict__ bucket_off,
                                                       const int* __restrict__ row_ptr, int* __restrict__ col) {
    __shared__ int rp[128];
    __shared__ int c[128];
    int tid = threadIdx.x;
    int node = blockIdx.x * 128 + tid;
    if (tid < 128) {
        rp[tid] = (node < N_NODES) ? row_ptr[node] : 0;
        c[tid] = 0;
    }
    __syncthreads();
    int s0 = bucket_off[blockIdx.x], s1 = bucket_off[blockIdx.x + 1];
    for (int i = s0 + tid; i < s1; i += 256) {
        int2 e = pairs[i];
        int dl = e.y & 127;
        int pos = rp[dl] + atomicAdd(&c[dl], 1);
        col[pos] = e.x;
    }
}

// ---------------- scan of deg -> row_ptr ----------------
#define SCAN_ELEMS 1024
__global__ __launch_bounds__(256) void scan_a_kernel(const int* __restrict__ deg, int* __restrict__ bsum) {
    __shared__ int lds[256];
    int tid = threadIdx.x;
    int base = blockIdx.x * SCAN_ELEMS + tid * 4;
    int s = 0;
    #pragma unroll
    for (int i = 0; i < 4; i++) {
        int idx = base + i;
        s += (idx < N_NODES) ? deg[idx] : 0;
    }
    lds[tid] = s;
    __syncthreads();
    for (int off = 128; off; off >>= 1) {
        if (tid < off) lds[tid] += lds[tid + off];
        __syncthreads();
    }
    if (tid == 0) bsum[blockIdx.x] = lds[0];
}

__global__ void scan_b_kernel(int* __restrict__ bsum, int nb) {
    if (threadIdx.x == 0 && blockIdx.x == 0) {
        int acc = 0;
        for (int i = 0; i < nb; i++) { int v = bsum[i]; bsum[i] = acc; acc += v; }
    }
}

__global__ __launch_bounds__(256) void scan_c_kernel(const int* __restrict__ deg, const int* __restrict__ bsum,
                                                     int* __restrict__ row_ptr) {
    __shared__ int lds[256];
    int tid = threadIdx.x;
    int base = blockIdx.x * SCAN_ELEMS + tid * 4;
    int v[4];
    int s = 0;
    #pragma unroll
    for (int i = 0; i < 4; i++) {
        int idx = base + i;
        v[i] = (idx < N_NODES) ? deg[idx] : 0;
        s += v[i];
    }
    lds[tid] = s;
    __syncthreads();
    for (int off = 1; off < 256; off <<= 1) {
        int y = 0;
        if (tid >= off) y = lds[tid - off];
        __syncthreads();
        if (tid >= off) lds[tid] += y;
        __syncthreads();
    }
    int run = bsum[blockIdx.x] + lds[tid] - s;
    #pragma unroll
    for (int i = 0; i < 4; i++) {
        int idx = base + i;
        if (idx < N_NODES) row_ptr[idx] = run;
        run += v[i];
    }
    if (blockIdx.x == 0 && tid == 0) row_ptr[N_NODES] = N_EDGES;
}

// ---------------- degree counting sort: ord[] = nodes sorted by degree ----------------
__global__ __launch_bounds__(256) void dsort_hist_kernel(const int* __restrict__ deg, int* __restrict__ dhist) {
    int i = blockIdx.x * 256 + threadIdx.x;
    if (i < N_NODES) atomicAdd(&dhist[min(deg[i], 63)], 1);
}

__global__ void dsort_scan_kernel(const int* __restrict__ dhist, int* __restrict__ dcur) {
    if (threadIdx.x == 0 && blockIdx.x == 0) {
        int acc = 0;
        for (int b = 0; b < 64; b++) { int v = dhist[b]; dcur[b] = acc; acc += v; }
    }
}

__global__ __launch_bounds__(256) void dsort_scat_kernel(const int* __restrict__ deg, int* __restrict__ dcur,
                                                         int* __restrict__ ord) {
    int i = blockIdx.x * 256 + threadIdx.x;
    if (i < N_NODES) {
        int pos = atomicAdd(&dcur[min(deg[i], 63)], 1);
        ord[pos] = i;
    }
}

// ---------------- x (fp32 Nx64) -> grouped bf16 slabs xg[g][node][16], g=0..3 ----------------
__global__ __launch_bounds__(256) void xbf_kernel(const float* __restrict__ x, unsigned short* __restrict__ xg) {
    int idx = blockIdx.x * 256 + threadIdx.x;   // one float4 per thread
    if (idx < N_NODES * 16) {
        int node = idx >> 4;
        int f0 = (idx & 15) * 4;
        float4 v = *(const float4*)(x + (size_t)idx * 4);
        ushort4 o;
        o.x = f2bf(v.x); o.y = f2bf(v.y); o.z = f2bf(v.z); o.w = f2bf(v.w);
        *(ushort4*)(xg + (size_t)(f0 >> 4) * (N_NODES * 16) + (size_t)node * 16 + (f0 & 15)) = o;
    }
}

// ---------------- grouped mean-aggregation, degree-sorted ----------------
// block = (chunk, g): g = blockIdx.x & ((1<<gshift)-1). 128 nodes/block in degree-sorted
// order (ord[]) -> uniform trip counts per wave. 2 lanes/node, uint4 (16 B = 8 bf16) loads.
// blockIdx%8 round-robin keeps each 3.2 MB slab hot in one XCD's L2.
__global__ __launch_bounds__(256) void aggG_kernel(const unsigned short* __restrict__ src,
                                                   unsigned short* __restrict__ dst,
                                                   const int* __restrict__ row_ptr, const int* __restrict__ col,
                                                   const int* __restrict__ ord, int gshift) {
    int tid = threadIdx.x;
    int g = blockIdx.x & ((1 << gshift) - 1);
    int chunk = blockIdx.x >> gshift;
    int slot = chunk * 128 + (tid >> 1);
    if (slot >= N_NODES) return;
    int i = ord[slot];
    int ld = (tid & 1) * 8;   // shorts offset within the 16-feat row
    const unsigned short* sg = src + (size_t)g * (N_NODES * 16) + ld;
    int s = row_ptr[i], e = row_ptr[i + 1];
    float a0 = 0.f, a1 = 0.f, a2 = 0.f, a3 = 0.f, a4 = 0.f, a5 = 0.f, a6 = 0.f, a7 = 0.f;
    int t = s;
    for (; t + 1 < e; t += 2) {
        int j0 = col[t], j1 = col[t + 1];
        uint4 u = *(const uint4*)(sg + (size_t)j0 * 16);
        uint4 v = *(const uint4*)(sg + (size_t)j1 * 16);
        a0 += __uint_as_float(u.x << 16) + __uint_as_float(v.x << 16);
        a1 += __uint_as_float(u.x & 0xFFFF0000u) + __uint_as_float(v.x & 0xFFFF0000u);
        a2 += __uint_as_float(u.y << 16) + __uint_as_float(v.y << 16);
        a3 += __uint_as_float(u.y & 0xFFFF0000u) + __uint_as_float(v.y & 0xFFFF0000u);
        a4 += __uint_as_float(u.z << 16) + __uint_as_float(v.z << 16);
        a5 += __uint_as_float(u.z & 0xFFFF0000u) + __uint_as_float(v.z & 0xFFFF0000u);
        a6 += __uint_as_float(u.w << 16) + __uint_as_float(v.w << 16);
        a7 += __uint_as_float(u.w & 0xFFFF0000u) + __uint_as_float(v.w & 0xFFFF0000u);
    }
    if (t < e) {
        uint4 u = *(const uint4*)(sg + (size_t)col[t] * 16);
        a0 += __uint_as_float(u.x << 16);
        a1 += __uint_as_float(u.x & 0xFFFF0000u);
        a2 += __uint_as_float(u.y << 16);
        a3 += __uint_as_float(u.y & 0xFFFF0000u);
        a4 += __uint_as_float(u.z << 16);
        a5 += __uint_as_float(u.z & 0xFFFF0000u);
        a6 += __uint_as_float(u.w << 16);
        a7 += __uint_as_float(u.w & 0xFFFF0000u);
    }
    float di = 1.0f / fmaxf((float)(e - s), 1.0f);
    unsigned int o0 = ((unsigned)f2bf(a1 * di) << 16) | f2bf(a0 * di);
    unsigned int o1 = ((unsigned)f2bf(a3 * di) << 16) | f2bf(a2 * di);
    unsigned int o2 = ((unsigned)f2bf(a5 * di) << 16) | f2bf(a4 * di);
    unsigned int o3 = ((unsigned)f2bf(a7 * di) << 16) | f2bf(a6 * di);
    *(uint4*)(dst + (size_t)g * (N_NODES * 16) + (size_t)i * 16 + ld) = make_uint4(o0, o1, o2, o3);
}

// ---------------- weight prep (transposed bf16) ----------------
// layer1: A = [x(k<64) | aggx(k>=64)], Bt1[n][k], n in [0,256), k in [0,128)
__global__ __launch_bounds__(256) void wprep1_kernel(const float* __restrict__ Wr1, const float* __restrict__ Wl1,
                                                     const float* __restrict__ Wres, unsigned short* __restrict__ Bt) {
    int idx = blockIdx.x * 256 + threadIdx.x;   // n*128 + k
    if (idx >= 256 * 128) return;
    int n = idx >> 7;
    int k = idx & 127;
    float v;
    if (n < 128) v = (k < 64) ? Wr1[k * 128 + n] : Wl1[(k - 64) * 128 + n];
    else         v = (k < 64) ? Wres[k * 128 + (n - 128)] : 0.f;
    Bt[idx] = f2bf(v);
}

// layers 2/3: A = [h(k<128) | aggh(k>=128)], Bt[n][k] = k<128 ? Wr[k][n] : Wl[k-128][n]
__global__ __launch_bounds__(256) void wprep23_kernel(const float* __restrict__ Wl, const float* __restrict__ Wr,
                                                      unsigned short* __restrict__ Bt) {
    int idx = blockIdx.x * 256 + threadIdx.x;   // n*256 + k
    if (idx >= 128 * 256) return;
    int n = idx >> 8;
    int k = idx & 255;
    float v = (k < 128) ? Wr[k * 128 + n] : Wl[(k - 128) * 128 + n];
    Bt[idx] = f2bf(v);
}

// ---------------- MFMA bf16 GEMM over grouped-slab A, grouped bf16 out ----------------
// A grouped: element (m, kk) at A[(kk>>4)*(N*16) + m*16 + (kk&15)]. Bt row-major [Nout][Kt].
// Output col cc = n0 + local; written to grouped slab (cc>>4). bias!=null -> +bias, relu.
// In-place over A slabs is safe: each block writes only rows it alone reads, after all reads.
__global__ __launch_bounds__(256) void mgemm_kernel(const unsigned short* __restrict__ A,
                                                    const unsigned short* __restrict__ Bt, int M, int Kt,
                                                    const float* __restrict__ bias,
                                                    unsigned short* __restrict__ Cbf) {
    __shared__ unsigned short As[128 * LP];
    __shared__ unsigned short Bs[128 * LP];
    int tid = threadIdx.x;
    int m0 = blockIdx.x * 128;
    int n0 = blockIdx.y * 128;

    int lane = tid & 63;
    int wave = tid >> 6;
    int wm = (wave & 1) * 64;
    int wn = (wave >> 1) * 64;
    int lm = lane & 15;
    int lk = (lane >> 4) * 8;

    float4v acc[4][4];
    #pragma unroll
    for (int i = 0; i < 4; i++)
        #pragma unroll
        for (int j = 0; j < 4; j++) acc[i][j] = (float4v)0.f;

    int sr = tid >> 3;          // staging row 0..31
    int sc = (tid & 7) * 8;     // staging col (shorts)

    for (int ks = 0; ks < Kt; ks += 64) {
        if (ks) __syncthreads();
        int kk = ks + sc;
        const unsigned short* Ab = A + (size_t)(kk >> 4) * (N_NODES * 16) + (kk & 15);
        #pragma unroll
        for (int rr = 0; rr < 128; rr += 32) {
            int r = sr + rr;
            int gm = m0 + r; if (gm > M - 1) gm = M - 1;
            ulonglong2 va = *(const ulonglong2*)(Ab + (size_t)gm * 16);
            *(ulonglong2*)&As[r * LP + sc] = va;
            ulonglong2 vb = *(const ulonglong2*)(Bt + (size_t)(n0 + r) * Kt + kk);
            *(ulonglong2*)&Bs[r * LP + sc] = vb;
        }
        __syncthreads();

        #pragma unroll
        for (int k0 = 0; k0 < 64; k0 += 32) {
            short8v af[4], bf[4];
            #pragma unroll
            for (int i = 0; i < 4; i++)
                af[i] = *(const short8v*)&As[(wm + i * 16 + lm) * LP + k0 + lk];
            #pragma unroll
            for (int j = 0; j < 4; j++)
                bf[j] = *(const short8v*)&Bs[(wn + j * 16 + lm) * LP + k0 + lk];
            #pragma unroll
            for (int i = 0; i < 4; i++)
                #pragma unroll
                for (int j = 0; j < 4; j++)
                    acc[i][j] = __builtin_amdgcn_mfma_f32_16x16x32_bf16(af[i], bf[j], acc[i][j], 0, 0, 0);
        }
    }

    int r0b = (lane >> 4) * 4;
    #pragma unroll
    for (int i = 0; i < 4; i++) {
        #pragma unroll
        for (int j = 0; j < 4; j++) {
            int cc = n0 + wn + j * 16 + (lane & 15);
            unsigned short* cp = Cbf + (size_t)(cc >> 4) * (N_NODES * 16) + (cc & 15);
            #pragma unroll
            for (int r = 0; r < 4; r++) {
                int m = m0 + wm + i * 16 + r0b + r;
                if (m < M) {
                    float v = acc[i][j][r];
                    if (bias != nullptr) v = fmaxf(v + bias[cc], 0.f);
                    cp[(size_t)m * 16] = f2bf(v);
                }
            }
        }
    }
}

// ---------------- layer1 epilogue: t=Ub[:,0:128]+b1 -> LN -> relu -> + Ub[:,128:256]+bres ----------------
__global__ __launch_bounds__(256) void ln_kernel(const unsigned short* __restrict__ Ub, const float* __restrict__ b1,
                                                 const float* __restrict__ ln_g, const float* __restrict__ ln_b,
                                                 const float* __restrict__ bres, unsigned short* __restrict__ act) {
    int tid = threadIdx.x;
    int grp = tid >> 7;
    int f = tid & 127;
    int i = blockIdx.x * 2 + grp;
    bool valid = i < N_NODES;
    float t = 0.f;
    if (valid) t = bf2f(Ub[(size_t)(f >> 4) * (N_NODES * 16) + (size_t)i * 16 + (f & 15)]) + b1[f];
    float s = t, s2 = t * t;
    #pragma unroll
    for (int off = 32; off; off >>= 1) {
        s += __shfl_down(s, off);
        s2 += __shfl_down(s2, off);
    }
    __shared__ float rs[4], rs2[4];
    int wave = tid >> 6;
    if ((tid & 63) == 0) { rs[wave] = s; rs2[wave] = s2; }
    __syncthreads();
    float sum = rs[grp * 2] + rs[grp * 2 + 1];
    float sumsq = rs2[grp * 2] + rs2[grp * 2 + 1];
    float mu = sum * (1.f / 128.f);
    float var = sumsq * (1.f / 128.f) - mu * mu;
    float r = rsqrtf(var + 1e-5f);
    if (valid) {
        float y = (t - mu) * r * ln_g[f] + ln_b[f];
        y = fmaxf(y, 0.f);
        y += bf2f(Ub[(size_t)((f >> 4) + 8) * (N_NODES * 16) + (size_t)i * 16 + (f & 15)]) + bres[f];
        act[(size_t)(f >> 4) * (N_NODES * 16) + (size_t)i * 16 + (f & 15)] = f2bf(y);
    }
}

// ---------------- layer4 ----------------
__global__ __launch_bounds__(256) void pq_kernel(const unsigned short* __restrict__ act, const float* __restrict__ Wl4,
                                                 const float* __restrict__ Wr4, const float* __restrict__ b4,
                                                 float* __restrict__ p, float* __restrict__ q) {
    int tid = threadIdx.x;
    int lane = tid & 63;
    int w = tid >> 6;
    int i = blockIdx.x * 4 + w;
    if (i >= N_NODES) return;
    int g0 = lane >> 4, o0 = lane & 15;
    float a = bf2f(act[(size_t)g0 * (N_NODES * 16) + (size_t)i * 16 + o0]);
    float b = bf2f(act[(size_t)(g0 + 4) * (N_NODES * 16) + (size_t)i * 16 + o0]);
    float pp = a * Wl4[lane] + b * Wl4[64 + lane];
    float qq = a * Wr4[lane] + b * Wr4[64 + lane];
    #pragma unroll
    for (int off = 32; off; off >>= 1) {
        pp += __shfl_down(pp, off);
        qq += __shfl_down(qq, off);
    }
    if (lane == 0) { p[i] = pp; q[i] = qq + b4[0]; }
}

__global__ __launch_bounds__(256) void final_kernel(const float* __restrict__ p, const float* __restrict__ q,
                                                    const int* __restrict__ row_ptr, const int* __restrict__ col,
                                                    float* __restrict__ out) {
    int i = blockIdx.x * 256 + threadIdx.x;
    if (i >= N_NODES) return;
    int s = row_ptr[i], e = row_ptr[i + 1];
    float acc = 0.f;
    for (int t = s; t < e; t++) acc += p[col[t]];
    float di = 1.0f / fmaxf((float)(e - s), 1.0f);
    out[i] = acc * di + q[i];
}

// ---------------- launch ----------------

extern "C" void kernel_launch(void* const* d_in, const int* in_sizes, int n_in,
                              void* d_out, int out_size, void* d_ws, size_t ws_size,
                              hipStream_t stream) {
    const float* x    = (const float*)d_in[0];
    const int*   ei   = (const int*)d_in[1];
    const float* Wl1  = (const float*)d_in[2];
    const float* Wr1  = (const float*)d_in[3];
    const float* b1   = (const float*)d_in[4];
    const float* ln_g = (const float*)d_in[5];
    const float* ln_b = (const float*)d_in[6];
    const float* Wres = (const float*)d_in[7];
    const float* bres = (const float*)d_in[8];
    const float* Wl2  = (const float*)d_in[9];
    const float* Wr2  = (const float*)d_in[10];
    const float* b2   = (const float*)d_in[11];
    const float* Wl3  = (const float*)d_in[12];
    const float* Wr3  = (const float*)d_in[13];
    const float* b3   = (const float*)d_in[14];
    const float* Wl4  = (const float*)d_in[15];
    const float* Wr4  = (const float*)d_in[16];
    const float* b4   = (const float*)d_in[17];
    float* out = (float*)d_out;

    char* w = (char*)d_ws;
    size_t off = 0;
    auto alloc = [&](size_t bytes) -> void* {
        off = (off + 255) & ~(size_t)255;
        void* pp = w + off;
        off += bytes;
        return pp;
    };

    int*   deg        = (int*)alloc(N_NODES * 4);
    int*   row_ptr    = (int*)alloc((N_NODES + 1) * 4);
    int*   bsum       = (int*)alloc(512);
    int*   col        = (int*)alloc(N_EDGES * 4);
    int*   bucket_cnt = (int*)alloc(NBKT * 4);
    int*   bucket_off = (int*)alloc((NBKT + 1) * 4);
    int*   cursor     = (int*)alloc(NBKT * 4);
    int*   dhist      = (int*)alloc(64 * 4);
    int*   dcur       = (int*)alloc(64 * 4);
    int*   ord        = (int*)alloc(N_NODES * 4);
    unsigned short* Btw  = (unsigned short*)alloc(128 * 256 * 2);
    unsigned short* xg   = (unsigned short*)alloc((size_t)8 * N_NODES * 16 * 2);   // [x g0-3 | aggx g4-7]
    unsigned short* act  = (unsigned short*)alloc((size_t)16 * N_NODES * 16 * 2);  // [h g0-7 | aggh g8-15]
    float* U       = (float*)alloc((size_t)N_NODES * 256 * 4);   // scratch: pairs, then Ub
    float* p       = (float*)alloc(N_NODES * 4);
    float* q       = (float*)alloc(N_NODES * 4);
    int2* pairs = (int2*)U;                  // CSR build scratch (done before U reused)
    unsigned short* Ub = (unsigned short*)U; // layer-1 GEMM out, 16 grouped bf16 slabs
    (void)ws_size; (void)n_in; (void)in_sizes; (void)out_size;

    const int NB = (N_NODES + 255) / 256;
    const int SCB = (N_NODES + SCAN_ELEMS - 1) / SCAN_ELEMS;
    const int MB = (N_NODES + 127) / 128;   // 782
    unsigned short* aggh = act + (size_t)8 * N_NODES * 16;

    // --- CSR build (bucket counting sort) ---
    hipMemsetAsync(bucket_cnt, 0, NBKT * 4, stream);
    hipMemsetAsync(dhist, 0, 64 * 4, stream);
    bkt_count_kernel<<<SCAT_BLOCKS, 256, 0, stream>>>(ei, bucket_cnt);
    bkt_scan_kernel<<<1, 256, 0, stream>>>(bucket_cnt, bucket_off, cursor);
    bkt_scatter_kernel<<<SCAT_BLOCKS, 256, 0, stream>>>(ei, cursor, pairs);
    bkt_deg_kernel<<<NBKT, 256, 0, stream>>>(pairs, bucket_off, deg);
    dsort_hist_kernel<<<NB, 256, 0, stream>>>(deg, dhist);
    dsort_scan_kernel<<<1, 64, 0, stream>>>(dhist, dcur);
    dsort_scat_kernel<<<NB, 256, 0, stream>>>(deg, dcur, ord);
    scan_a_kernel<<<SCB, 256, 0, stream>>>(deg, bsum);
    scan_b_kernel<<<1, 64, 0, stream>>>(bsum, SCB);
    scan_c_kernel<<<SCB, 256, 0, stream>>>(deg, bsum, row_ptr);
    bkt_fill_kernel<<<NBKT, 256, 0, stream>>>(pairs, bucket_off, row_ptr, col);

    // --- layer 1: xg = [x | mean-agg(x)] grouped bf16; GEMM -> Ub bf16; LN -> act ---
    xbf_kernel<<<(N_NODES * 16 + 255) / 256, 256, 0, stream>>>(x, xg);
    aggG_kernel<<<MB * 4, 256, 0, stream>>>(xg, xg + (size_t)4 * N_NODES * 16, row_ptr, col, ord, 2);
    wprep1_kernel<<<128, 256, 0, stream>>>(Wr1, Wl1, Wres, Btw);
    mgemm_kernel<<<dim3(MB, 2), 256, 0, stream>>>(xg, Btw, N_NODES, 128, nullptr, Ub);
    ln_kernel<<<(N_NODES + 1) / 2, 256, 0, stream>>>(Ub, b1, ln_g, ln_b, bres, act);

    // --- layer 2: agg(h) -> aggh; GEMM [h|aggh] -> h (in-place, fused bias+relu) ---
    aggG_kernel<<<MB * 8, 256, 0, stream>>>(act, aggh, row_ptr, col, ord, 3);
    wprep23_kernel<<<128, 256, 0, stream>>>(Wl2, Wr2, Btw);
    mgemm_kernel<<<dim3(MB, 1), 256, 0, stream>>>(act, Btw, N_NODES, 256, b2, act);

    // --- layer 3 ---
    aggG_kernel<<<MB * 8, 256, 0, stream>>>(act, aggh, row_ptr, col, ord, 3);
    wprep23_kernel<<<128, 256, 0, stream>>>(Wl3, Wr3, Btw);
    mgemm_kernel<<<dim3(MB, 1), 256, 0, stream>>>(act, Btw, N_NODES, 256, b3, act);

    // --- layer 4 ---
    pq_kernel<<<(N_NODES + 3) / 4, 256, 0, stream>>>(act, Wl4, Wr4, b4, p, q);
    final_kernel<<<NB, 256, 0, stream>>>(p, q, row_ptr, col, out);
}

// Round 7
// 646.348 us; speedup vs baseline: 2.0814x; 2.0814x over previous
//
#include <hip/hip_runtime.h>
#include <hip/hip_bf16.h>

#define N_NODES 100000
#define N_EDGES 1600000

#define NBKT 782                 // ceil(N_NODES / 128)
#define BKT_CHUNK 13334          // ceil(N_EDGES / 120)
#define SCAT_BLOCKS 120
#define LP 72                    // padded LDS row length in shorts (64 + 8)

#define SORT_BLOCKS 40
#define SORT_CHUNK 2500          // 40 * 2500 = 100000

typedef __attribute__((ext_vector_type(8))) short short8v;
typedef __attribute__((ext_vector_type(4))) float float4v;

__device__ __forceinline__ unsigned short f2bf(float f) {
    unsigned int u = __float_as_uint(f);
    u = (u + 0x7FFFu + ((u >> 16) & 1u)) >> 16;   // RTNE
    return (unsigned short)u;
}
__device__ __forceinline__ float bf2f(unsigned short b) {
    return __uint_as_float((unsigned int)b << 16);
}

// ---------------- CSR build via 2-level bucket counting sort (dst buckets) ----------------

__global__ __launch_bounds__(256) void bkt_count_kernel(const int* __restrict__ ei, int* __restrict__ bucket_cnt) {
    __shared__ int h[NBKT];
    int tid = threadIdx.x;
    for (int i = tid; i < NBKT; i += 256) h[i] = 0;
    __syncthreads();
    int start = blockIdx.x * BKT_CHUNK;
    int end = start + BKT_CHUNK; if (end > N_EDGES) end = N_EDGES;
    for (int i = start + tid; i < end; i += 256) {
        int d = ei[N_EDGES + i];
        atomicAdd(&h[d >> 7], 1);
    }
    __syncthreads();
    for (int i = tid; i < NBKT; i += 256) {
        int c = h[i];
        if (c) atomicAdd(&bucket_cnt[i], c);
    }
}

__global__ __launch_bounds__(256) void bkt_scan_kernel(const int* __restrict__ bucket_cnt,
                                                       int* __restrict__ bucket_off, int* __restrict__ cursor) {
    __shared__ int ps[256];
    int tid = threadIdx.x;
    int base = tid * 4;
    int v[4];
    int s = 0;
    #pragma unroll
    for (int i = 0; i < 4; i++) {
        v[i] = (base + i < NBKT) ? bucket_cnt[base + i] : 0;
        s += v[i];
    }
    ps[tid] = s;
    __syncthreads();
    for (int off = 1; off < 256; off <<= 1) {
        int y = 0;
        if (tid >= off) y = ps[tid - off];
        __syncthreads();
        if (tid >= off) ps[tid] += y;
        __syncthreads();
    }
    int run = ps[tid] - s;   // exclusive
    #pragma unroll
    for (int i = 0; i < 4; i++) {
        if (base + i < NBKT) { bucket_off[base + i] = run; cursor[base + i] = run; }
        run += v[i];
    }
    if (tid == 0) bucket_off[NBKT] = N_EDGES;
}

__global__ __launch_bounds__(256) void bkt_scatter_kernel(const int* __restrict__ ei, int* __restrict__ cursor,
                                                          int2* __restrict__ pairs) {
    __shared__ int h[NBKT];
    __shared__ int basearr[NBKT];
    int tid = threadIdx.x;
    for (int i = tid; i < NBKT; i += 256) h[i] = 0;
    __syncthreads();
    int start = blockIdx.x * BKT_CHUNK;
    int end = start + BKT_CHUNK; if (end > N_EDGES) end = N_EDGES;
    for (int i = start + tid; i < end; i += 256) {
        int d = ei[N_EDGES + i];
        atomicAdd(&h[d >> 7], 1);
    }
    __syncthreads();
    for (int b = tid; b < NBKT; b += 256) {
        int c = h[b];
        basearr[b] = c ? atomicAdd(&cursor[b], c) : 0;
        h[b] = 0;
    }
    __syncthreads();
    for (int i = start + tid; i < end; i += 256) {
        int s = ei[i];
        int d = ei[N_EDGES + i];
        int bkt = d >> 7;
        int pos = basearr[bkt] + atomicAdd(&h[bkt], 1);
        pairs[pos] = make_int2(s, d);
    }
}

__global__ __launch_bounds__(256) void bkt_deg_kernel(const int2* __restrict__ pairs, const int* __restrict__ bucket_off,
                                                      int* __restrict__ deg) {
    __shared__ int c[128];
    int tid = threadIdx.x;
    if (tid < 128) c[tid] = 0;
    __syncthreads();
    int s0 = bucket_off[blockIdx.x], s1 = bucket_off[blockIdx.x + 1];
    for (int i = s0 + tid; i < s1; i += 256) {
        int d = pairs[i].y;
        atomicAdd(&c[d & 127], 1);
    }
    __syncthreads();
    int node = blockIdx.x * 128 + tid;
    if (tid < 128 && node < N_NODES) deg[node] = c[tid];
}

// CSR fill in SORTED space: position from row_ptr[rank[dst]], col value = rank[src]
__global__ __launch_bounds__(256) void bkt_fill_kernel(const int2* __restrict__ pairs, const int* __restrict__ bucket_off,
                                                       const int* __restrict__ row_ptr, const int* __restrict__ rank,
                                                       int* __restrict__ col) {
    __shared__ int rp[128];
    __shared__ int c[128];
    int tid = threadIdx.x;
    int node = blockIdx.x * 128 + tid;
    if (tid < 128) {
        rp[tid] = (node < N_NODES) ? row_ptr[rank[node]] : 0;
        c[tid] = 0;
    }
    __syncthreads();
    int s0 = bucket_off[blockIdx.x], s1 = bucket_off[blockIdx.x + 1];
    for (int i = s0 + tid; i < s1; i += 256) {
        int2 e = pairs[i];
        int dl = e.y & 127;
        int pos = rp[dl] + atomicAdd(&c[dl], 1);
        col[pos] = rank[e.x];
    }
}

// ---------------- degree counting sort (contention-free: per-block hists + scan) ----------------
// bh layout: bin-major, bh[bin * SORT_BLOCKS + blk]

__global__ __launch_bounds__(256) void dsort_hist_kernel(const int* __restrict__ deg, int* __restrict__ bh) {
    __shared__ int h[64];
    int tid = threadIdx.x;
    if (tid < 64) h[tid] = 0;
    __syncthreads();
    int start = blockIdx.x * SORT_CHUNK;
    int end = start + SORT_CHUNK; if (end > N_NODES) end = N_NODES;
    for (int i = start + tid; i < end; i += 256) atomicAdd(&h[min(deg[i], 63)], 1);
    __syncthreads();
    if (tid < 64) bh[tid * SORT_BLOCKS + blockIdx.x] = h[tid];
}

// exclusive scan over all 64*SORT_BLOCKS = 2560 counts (in place)
__global__ __launch_bounds__(256) void dsort_scan_kernel(int* __restrict__ bh) {
    __shared__ int ps[256];
    int tid = threadIdx.x;
    int v[10];
    int s = 0;
    #pragma unroll
    for (int k = 0; k < 10; k++) { v[k] = bh[tid * 10 + k]; s += v[k]; }
    ps[tid] = s;
    __syncthreads();
    for (int off = 1; off < 256; off <<= 1) {
        int y = 0;
        if (tid >= off) y = ps[tid - off];
        __syncthreads();
        if (tid >= off) ps[tid] += y;
        __syncthreads();
    }
    int run = ps[tid] - s;
    #pragma unroll
    for (int k = 0; k < 10; k++) { int t = v[k]; bh[tid * 10 + k] = run; run += t; }
}

// scatter: pos = scanned base(bin, blk) + LDS-local rank. Writes ord, rank, sorted deg.
__global__ __launch_bounds__(256) void dsort_scat_kernel(const int* __restrict__ deg, const int* __restrict__ bh,
                                                         int* __restrict__ ord, int* __restrict__ rank,
                                                         int* __restrict__ deg_s) {
    __shared__ int h[64];
    __shared__ int base[64];
    int tid = threadIdx.x;
    if (tid < 64) { h[tid] = 0; base[tid] = bh[tid * SORT_BLOCKS + blockIdx.x]; }
    __syncthreads();
    int start = blockIdx.x * SORT_CHUNK;
    int end = start + SORT_CHUNK; if (end > N_NODES) end = N_NODES;
    for (int i = start + tid; i < end; i += 256) {
        int d = deg[i];
        int b = min(d, 63);
        int pos = base[b] + atomicAdd(&h[b], 1);
        ord[pos] = i;
        rank[i] = pos;
        deg_s[pos] = d;
    }
}

// ---------------- scan of deg_s -> row_ptr (sorted space) ----------------
#define SCAN_ELEMS 1024
__global__ __launch_bounds__(256) void scan_a_kernel(const int* __restrict__ deg, int* __restrict__ bsum) {
    __shared__ int lds[256];
    int tid = threadIdx.x;
    int base = blockIdx.x * SCAN_ELEMS + tid * 4;
    int s = 0;
    #pragma unroll
    for (int i = 0; i < 4; i++) {
        int idx = base + i;
        s += (idx < N_NODES) ? deg[idx] : 0;
    }
    lds[tid] = s;
    __syncthreads();
    for (int off = 128; off; off >>= 1) {
        if (tid < off) lds[tid] += lds[tid + off];
        __syncthreads();
    }
    if (tid == 0) bsum[blockIdx.x] = lds[0];
}

__global__ void scan_b_kernel(int* __restrict__ bsum, int nb) {
    if (threadIdx.x == 0 && blockIdx.x == 0) {
        int acc = 0;
        for (int i = 0; i < nb; i++) { int v = bsum[i]; bsum[i] = acc; acc += v; }
    }
}

__global__ __launch_bounds__(256) void scan_c_kernel(const int* __restrict__ deg, const int* __restrict__ bsum,
                                                     int* __restrict__ row_ptr) {
    __shared__ int lds[256];
    int tid = threadIdx.x;
    int base = blockIdx.x * SCAN_ELEMS + tid * 4;
    int v[4];
    int s = 0;
    #pragma unroll
    for (int i = 0; i < 4; i++) {
        int idx = base + i;
        v[i] = (idx < N_NODES) ? deg[idx] : 0;
        s += v[i];
    }
    lds[tid] = s;
    __syncthreads();
    for (int off = 1; off < 256; off <<= 1) {
        int y = 0;
        if (tid >= off) y = lds[tid - off];
        __syncthreads();
        if (tid >= off) lds[tid] += y;
        __syncthreads();
    }
    int run = bsum[blockIdx.x] + lds[tid] - s;
    #pragma unroll
    for (int i = 0; i < 4; i++) {
        int idx = base + i;
        if (idx < N_NODES) row_ptr[idx] = run;
        run += v[i];
    }
    if (blockIdx.x == 0 && tid == 0) row_ptr[N_NODES] = N_EDGES;
}

// ---------------- x (fp32 Nx64) -> grouped bf16 slabs at SORTED position ----------------
__global__ __launch_bounds__(256) void xbf_kernel(const float* __restrict__ x, const int* __restrict__ rank,
                                                  unsigned short* __restrict__ xg) {
    int idx = blockIdx.x * 256 + threadIdx.x;   // one float4 per thread
    if (idx < N_NODES * 16) {
        int node = idx >> 4;
        int f0 = (idx & 15) * 4;
        int rn = rank[node];
        float4 v = *(const float4*)(x + (size_t)idx * 4);
        ushort4 o;
        o.x = f2bf(v.x); o.y = f2bf(v.y); o.z = f2bf(v.z); o.w = f2bf(v.w);
        *(ushort4*)(xg + (size_t)(f0 >> 4) * (N_NODES * 16) + (size_t)rn * 16 + (f0 & 15)) = o;
    }
}

// ---------------- grouped mean-aggregation in sorted space ----------------
// Everything indexed by sorted slot: row_ptr/col/src/dst all sorted-space.
// 128 nodes/block, 2 lanes/node, uint4 (8 bf16) loads; degrees uniform within a wave
// (sorted); writes fully coalesced. blockIdx%8 keeps one 3.2MB slab per XCD L2.
__global__ __launch_bounds__(256) void aggG_kernel(const unsigned short* __restrict__ src,
                                                   unsigned short* __restrict__ dst,
                                                   const int* __restrict__ row_ptr, const int* __restrict__ col,
                                                   int gshift) {
    int tid = threadIdx.x;
    int g = blockIdx.x & ((1 << gshift) - 1);
    int chunk = blockIdx.x >> gshift;
    int i = chunk * 128 + (tid >> 1);
    if (i >= N_NODES) return;
    int ld = (tid & 1) * 8;   // shorts offset within the 16-feat row
    const unsigned short* sg = src + (size_t)g * (N_NODES * 16) + ld;
    int s = row_ptr[i], e = row_ptr[i + 1];
    float a0 = 0.f, a1 = 0.f, a2 = 0.f, a3 = 0.f, a4 = 0.f, a5 = 0.f, a6 = 0.f, a7 = 0.f;
    int t = s;
    for (; t + 1 < e; t += 2) {
        int j0 = col[t], j1 = col[t + 1];
        uint4 u = *(const uint4*)(sg + (size_t)j0 * 16);
        uint4 v = *(const uint4*)(sg + (size_t)j1 * 16);
        a0 += __uint_as_float(u.x << 16) + __uint_as_float(v.x << 16);
        a1 += __uint_as_float(u.x & 0xFFFF0000u) + __uint_as_float(v.x & 0xFFFF0000u);
        a2 += __uint_as_float(u.y << 16) + __uint_as_float(v.y << 16);
        a3 += __uint_as_float(u.y & 0xFFFF0000u) + __uint_as_float(v.y & 0xFFFF0000u);
        a4 += __uint_as_float(u.z << 16) + __uint_as_float(v.z << 16);
        a5 += __uint_as_float(u.z & 0xFFFF0000u) + __uint_as_float(v.z & 0xFFFF0000u);
        a6 += __uint_as_float(u.w << 16) + __uint_as_float(v.w << 16);
        a7 += __uint_as_float(u.w & 0xFFFF0000u) + __uint_as_float(v.w & 0xFFFF0000u);
    }
    if (t < e) {
        uint4 u = *(const uint4*)(sg + (size_t)col[t] * 16);
        a0 += __uint_as_float(u.x << 16);
        a1 += __uint_as_float(u.x & 0xFFFF0000u);
        a2 += __uint_as_float(u.y << 16);
        a3 += __uint_as_float(u.y & 0xFFFF0000u);
        a4 += __uint_as_float(u.z << 16);
        a5 += __uint_as_float(u.z & 0xFFFF0000u);
        a6 += __uint_as_float(u.w << 16);
        a7 += __uint_as_float(u.w & 0xFFFF0000u);
    }
    float di = 1.0f / fmaxf((float)(e - s), 1.0f);
    unsigned int o0 = ((unsigned)f2bf(a1 * di) << 16) | f2bf(a0 * di);
    unsigned int o1 = ((unsigned)f2bf(a3 * di) << 16) | f2bf(a2 * di);
    unsigned int o2 = ((unsigned)f2bf(a5 * di) << 16) | f2bf(a4 * di);
    unsigned int o3 = ((unsigned)f2bf(a7 * di) << 16) | f2bf(a6 * di);
    *(uint4*)(dst + (size_t)g * (N_NODES * 16) + (size_t)i * 16 + ld) = make_uint4(o0, o1, o2, o3);
}

// ---------------- weight prep (transposed bf16) ----------------
__global__ __launch_bounds__(256) void wprep1_kernel(const float* __restrict__ Wr1, const float* __restrict__ Wl1,
                                                     const float* __restrict__ Wres, unsigned short* __restrict__ Bt) {
    int idx = blockIdx.x * 256 + threadIdx.x;   // n*128 + k
    if (idx >= 256 * 128) return;
    int n = idx >> 7;
    int k = idx & 127;
    float v;
    if (n < 128) v = (k < 64) ? Wr1[k * 128 + n] : Wl1[(k - 64) * 128 + n];
    else         v = (k < 64) ? Wres[k * 128 + (n - 128)] : 0.f;
    Bt[idx] = f2bf(v);
}

__global__ __launch_bounds__(256) void wprep23_kernel(const float* __restrict__ Wl, const float* __restrict__ Wr,
                                                      unsigned short* __restrict__ Bt) {
    int idx = blockIdx.x * 256 + threadIdx.x;   // n*256 + k
    if (idx >= 128 * 256) return;
    int n = idx >> 8;
    int k = idx & 255;
    float v = (k < 128) ? Wr[k * 128 + n] : Wl[(k - 128) * 128 + n];
    Bt[idx] = f2bf(v);
}

// ---------------- MFMA bf16 GEMM over grouped-slab A, grouped bf16 out ----------------
__global__ __launch_bounds__(256) void mgemm_kernel(const unsigned short* __restrict__ A,
                                                    const unsigned short* __restrict__ Bt, int M, int Kt,
                                                    const float* __restrict__ bias,
                                                    unsigned short* __restrict__ Cbf) {
    __shared__ unsigned short As[128 * LP];
    __shared__ unsigned short Bs[128 * LP];
    int tid = threadIdx.x;
    int m0 = blockIdx.x * 128;
    int n0 = blockIdx.y * 128;

    int lane = tid & 63;
    int wave = tid >> 6;
    int wm = (wave & 1) * 64;
    int wn = (wave >> 1) * 64;
    int lm = lane & 15;
    int lk = (lane >> 4) * 8;

    float4v acc[4][4];
    #pragma unroll
    for (int i = 0; i < 4; i++)
        #pragma unroll
        for (int j = 0; j < 4; j++) acc[i][j] = (float4v)0.f;

    int sr = tid >> 3;          // staging row 0..31
    int sc = (tid & 7) * 8;     // staging col (shorts)

    for (int ks = 0; ks < Kt; ks += 64) {
        if (ks) __syncthreads();
        int kk = ks + sc;
        const unsigned short* Ab = A + (size_t)(kk >> 4) * (N_NODES * 16) + (kk & 15);
        #pragma unroll
        for (int rr = 0; rr < 128; rr += 32) {
            int r = sr + rr;
            int gm = m0 + r; if (gm > M - 1) gm = M - 1;
            ulonglong2 va = *(const ulonglong2*)(Ab + (size_t)gm * 16);
            *(ulonglong2*)&As[r * LP + sc] = va;
            ulonglong2 vb = *(const ulonglong2*)(Bt + (size_t)(n0 + r) * Kt + kk);
            *(ulonglong2*)&Bs[r * LP + sc] = vb;
        }
        __syncthreads();

        #pragma unroll
        for (int k0 = 0; k0 < 64; k0 += 32) {
            short8v af[4], bf[4];
            #pragma unroll
            for (int i = 0; i < 4; i++)
                af[i] = *(const short8v*)&As[(wm + i * 16 + lm) * LP + k0 + lk];
            #pragma unroll
            for (int j = 0; j < 4; j++)
                bf[j] = *(const short8v*)&Bs[(wn + j * 16 + lm) * LP + k0 + lk];
            #pragma unroll
            for (int i = 0; i < 4; i++)
                #pragma unroll
                for (int j = 0; j < 4; j++)
                    acc[i][j] = __builtin_amdgcn_mfma_f32_16x16x32_bf16(af[i], bf[j], acc[i][j], 0, 0, 0);
        }
    }

    int r0b = (lane >> 4) * 4;
    #pragma unroll
    for (int i = 0; i < 4; i++) {
        #pragma unroll
        for (int j = 0; j < 4; j++) {
            int cc = n0 + wn + j * 16 + (lane & 15);
            unsigned short* cp = Cbf + (size_t)(cc >> 4) * (N_NODES * 16) + (cc & 15);
            #pragma unroll
            for (int r = 0; r < 4; r++) {
                int m = m0 + wm + i * 16 + r0b + r;
                if (m < M) {
                    float v = acc[i][j][r];
                    if (bias != nullptr) v = fmaxf(v + bias[cc], 0.f);
                    cp[(size_t)m * 16] = f2bf(v);
                }
            }
        }
    }
}

// ---------------- layer1 epilogue ----------------
__global__ __launch_bounds__(256) void ln_kernel(const unsigned short* __restrict__ Ub, const float* __restrict__ b1,
                                                 const float* __restrict__ ln_g, const float* __restrict__ ln_b,
                                                 const float* __restrict__ bres, unsigned short* __restrict__ act) {
    int tid = threadIdx.x;
    int grp = tid >> 7;
    int f = tid & 127;
    int i = blockIdx.x * 2 + grp;
    bool valid = i < N_NODES;
    float t = 0.f;
    if (valid) t = bf2f(Ub[(size_t)(f >> 4) * (N_NODES * 16) + (size_t)i * 16 + (f & 15)]) + b1[f];
    float s = t, s2 = t * t;
    #pragma unroll
    for (int off = 32; off; off >>= 1) {
        s += __shfl_down(s, off);
        s2 += __shfl_down(s2, off);
    }
    __shared__ float rs[4], rs2[4];
    int wave = tid >> 6;
    if ((tid & 63) == 0) { rs[wave] = s; rs2[wave] = s2; }
    __syncthreads();
    float sum = rs[grp * 2] + rs[grp * 2 + 1];
    float sumsq = rs2[grp * 2] + rs2[grp * 2 + 1];
    float mu = sum * (1.f / 128.f);
    float var = sumsq * (1.f / 128.f) - mu * mu;
    float r = rsqrtf(var + 1e-5f);
    if (valid) {
        float y = (t - mu) * r * ln_g[f] + ln_b[f];
        y = fmaxf(y, 0.f);
        y += bf2f(Ub[(size_t)((f >> 4) + 8) * (N_NODES * 16) + (size_t)i * 16 + (f & 15)]) + bres[f];
        act[(size_t)(f >> 4) * (N_NODES * 16) + (size_t)i * 16 + (f & 15)] = f2bf(y);
    }
}

// ---------------- layer4 (sorted space) ----------------
__global__ __launch_bounds__(256) void pq_kernel(const unsigned short* __restrict__ act, const float* __restrict__ Wl4,
                                                 const float* __restrict__ Wr4, const float* __restrict__ b4,
                                                 float* __restrict__ p, float* __restrict__ q) {
    int tid = threadIdx.x;
    int lane = tid & 63;
    int w = tid >> 6;
    int i = blockIdx.x * 4 + w;
    if (i >= N_NODES) return;
    int g0 = lane >> 4, o0 = lane & 15;
    float a = bf2f(act[(size_t)g0 * (N_NODES * 16) + (size_t)i * 16 + o0]);
    float b = bf2f(act[(size_t)(g0 + 4) * (N_NODES * 16) + (size_t)i * 16 + o0]);
    float pp = a * Wl4[lane] + b * Wl4[64 + lane];
    float qq = a * Wr4[lane] + b * Wr4[64 + lane];
    #pragma unroll
    for (int off = 32; off; off >>= 1) {
        pp += __shfl_down(pp, off);
        qq += __shfl_down(qq, off);
    }
    if (lane == 0) { p[i] = pp; q[i] = qq + b4[0]; }
}

__global__ __launch_bounds__(256) void final_kernel(const float* __restrict__ p, const float* __restrict__ q,
                                                    const int* __restrict__ row_ptr, const int* __restrict__ col,
                                                    const int* __restrict__ ord, float* __restrict__ out) {
    int i = blockIdx.x * 256 + threadIdx.x;   // sorted slot
    if (i >= N_NODES) return;
    int s = row_ptr[i], e = row_ptr[i + 1];
    float acc = 0.f;
    for (int t = s; t < e; t++) acc += p[col[t]];
    float di = 1.0f / fmaxf((float)(e - s), 1.0f);
    out[ord[i]] = acc * di + q[i];
}

// ---------------- launch ----------------

extern "C" void kernel_launch(void* const* d_in, const int* in_sizes, int n_in,
                              void* d_out, int out_size, void* d_ws, size_t ws_size,
                              hipStream_t stream) {
    const float* x    = (const float*)d_in[0];
    const int*   ei   = (const int*)d_in[1];
    const float* Wl1  = (const float*)d_in[2];
    const float* Wr1  = (const float*)d_in[3];
    const float* b1   = (const float*)d_in[4];
    const float* ln_g = (const float*)d_in[5];
    const float* ln_b = (const float*)d_in[6];
    const float* Wres = (const float*)d_in[7];
    const float* bres = (const float*)d_in[8];
    const float* Wl2  = (const float*)d_in[9];
    const float* Wr2  = (const float*)d_in[10];
    const float* b2   = (const float*)d_in[11];
    const float* Wl3  = (const float*)d_in[12];
    const float* Wr3  = (const float*)d_in[13];
    const float* b3   = (const float*)d_in[14];
    const float* Wl4  = (const float*)d_in[15];
    const float* Wr4  = (const float*)d_in[16];
    const float* b4   = (const float*)d_in[17];
    float* out = (float*)d_out;

    char* w = (char*)d_ws;
    size_t off = 0;
    auto alloc = [&](size_t bytes) -> void* {
        off = (off + 255) & ~(size_t)255;
        void* pp = w + off;
        off += bytes;
        return pp;
    };

    int*   deg        = (int*)alloc(N_NODES * 4);       // original space
    int*   deg_s      = (int*)alloc(N_NODES * 4);       // sorted space
    int*   row_ptr    = (int*)alloc((N_NODES + 1) * 4); // sorted space
    int*   bsum       = (int*)alloc(512);
    int*   col        = (int*)alloc(N_EDGES * 4);       // sorted-space src ids
    int*   bucket_cnt = (int*)alloc(NBKT * 4);
    int*   bucket_off = (int*)alloc((NBKT + 1) * 4);
    int*   cursor     = (int*)alloc(NBKT * 4);
    int*   bh         = (int*)alloc(64 * SORT_BLOCKS * 4);
    int*   ord        = (int*)alloc(N_NODES * 4);       // slot -> orig
    int*   rank       = (int*)alloc(N_NODES * 4);       // orig -> slot
    unsigned short* Btw  = (unsigned short*)alloc(128 * 256 * 2);
    unsigned short* xg   = (unsigned short*)alloc((size_t)8 * N_NODES * 16 * 2);   // [x g0-3 | aggx g4-7]
    unsigned short* act  = (unsigned short*)alloc((size_t)16 * N_NODES * 16 * 2);  // [h g0-7 | aggh g8-15]
    float* U       = (float*)alloc((size_t)N_NODES * 256 * 4);   // scratch: pairs, then Ub
    float* p       = (float*)alloc(N_NODES * 4);
    float* q       = (float*)alloc(N_NODES * 4);
    int2* pairs = (int2*)U;                  // CSR build scratch (done before U reused)
    unsigned short* Ub = (unsigned short*)U; // layer-1 GEMM out, 16 grouped bf16 slabs
    (void)ws_size; (void)n_in; (void)in_sizes; (void)out_size;

    const int NB = (N_NODES + 255) / 256;
    const int SCB = (N_NODES + SCAN_ELEMS - 1) / SCAN_ELEMS;
    const int MB = (N_NODES + 127) / 128;   // 782
    unsigned short* aggh = act + (size_t)8 * N_NODES * 16;

    // --- CSR build (dst-bucket sort; fill into degree-sorted node space) ---
    hipMemsetAsync(bucket_cnt, 0, NBKT * 4, stream);
    bkt_count_kernel<<<SCAT_BLOCKS, 256, 0, stream>>>(ei, bucket_cnt);
    bkt_scan_kernel<<<1, 256, 0, stream>>>(bucket_cnt, bucket_off, cursor);
    bkt_scatter_kernel<<<SCAT_BLOCKS, 256, 0, stream>>>(ei, cursor, pairs);
    bkt_deg_kernel<<<NBKT, 256, 0, stream>>>(pairs, bucket_off, deg);
    dsort_hist_kernel<<<SORT_BLOCKS, 256, 0, stream>>>(deg, bh);
    dsort_scan_kernel<<<1, 256, 0, stream>>>(bh);
    dsort_scat_kernel<<<SORT_BLOCKS, 256, 0, stream>>>(deg, bh, ord, rank, deg_s);
    scan_a_kernel<<<SCB, 256, 0, stream>>>(deg_s, bsum);
    scan_b_kernel<<<1, 64, 0, stream>>>(bsum, SCB);
    scan_c_kernel<<<SCB, 256, 0, stream>>>(deg_s, bsum, row_ptr);
    bkt_fill_kernel<<<NBKT, 256, 0, stream>>>(pairs, bucket_off, row_ptr, rank, col);

    // --- layer 1: xg = [x | mean-agg(x)] grouped bf16 (sorted space); GEMM -> Ub; LN -> act ---
    xbf_kernel<<<(N_NODES * 16 + 255) / 256, 256, 0, stream>>>(x, rank, xg);
    aggG_kernel<<<MB * 4, 256, 0, stream>>>(xg, xg + (size_t)4 * N_NODES * 16, row_ptr, col, 2);
    wprep1_kernel<<<128, 256, 0, stream>>>(Wr1, Wl1, Wres, Btw);
    mgemm_kernel<<<dim3(MB, 2), 256, 0, stream>>>(xg, Btw, N_NODES, 128, nullptr, Ub);
    ln_kernel<<<(N_NODES + 1) / 2, 256, 0, stream>>>(Ub, b1, ln_g, ln_b, bres, act);

    // --- layer 2: agg(h) -> aggh; GEMM [h|aggh] -> h (in-place, fused bias+relu) ---
    aggG_kernel<<<MB * 8, 256, 0, stream>>>(act, aggh, row_ptr, col, 3);
    wprep23_kernel<<<128, 256, 0, stream>>>(Wl2, Wr2, Btw);
    mgemm_kernel<<<dim3(MB, 1), 256, 0, stream>>>(act, Btw, N_NODES, 256, b2, act);

    // --- layer 3 ---
    aggG_kernel<<<MB * 8, 256, 0, stream>>>(act, aggh, row_ptr, col, 3);
    wprep23_kernel<<<128, 256, 0, stream>>>(Wl3, Wr3, Btw);
    mgemm_kernel<<<dim3(MB, 1), 256, 0, stream>>>(act, Btw, N_NODES, 256, b3, act);

    // --- layer 4 ---
    pq_kernel<<<(N_NODES + 3) / 4, 256, 0, stream>>>(act, Wl4, Wr4, b4, p, q);
    final_kernel<<<NB, 256, 0, stream>>>(p, q, row_ptr, col, ord, out);
}

// Round 8
// 544.273 us; speedup vs baseline: 2.4717x; 1.1875x over previous
//
#include <hip/hip_runtime.h>
#include <hip/hip_bf16.h>

#define N_NODES 100000
#define N_EDGES 1600000

#define NBKT 782                 // ceil(N_NODES / 128)
#define BKT_CHUNK 13334          // ceil(N_EDGES / 120)
#define SCAT_BLOCKS 120
#define LP 72                    // padded LDS row length in shorts (64 + 8)

#define SORT_BLOCKS 40
#define SORT_CHUNK 2500          // 40 * 2500 = 100000

typedef __attribute__((ext_vector_type(8))) short short8v;
typedef __attribute__((ext_vector_type(4))) float float4v;

__device__ __forceinline__ unsigned short f2bf(float f) {
    unsigned int u = __float_as_uint(f);
    u = (u + 0x7FFFu + ((u >> 16) & 1u)) >> 16;   // RTNE
    return (unsigned short)u;
}
__device__ __forceinline__ float bf2f(unsigned short b) {
    return __uint_as_float((unsigned int)b << 16);
}

// ---------------- CSR build via 2-level bucket counting sort (dst buckets) ----------------

__global__ __launch_bounds__(256) void bkt_count_kernel(const int* __restrict__ ei, int* __restrict__ bucket_cnt) {
    __shared__ int h[NBKT];
    int tid = threadIdx.x;
    for (int i = tid; i < NBKT; i += 256) h[i] = 0;
    __syncthreads();
    int start = blockIdx.x * BKT_CHUNK;
    int end = start + BKT_CHUNK; if (end > N_EDGES) end = N_EDGES;
    for (int i = start + tid; i < end; i += 256) {
        int d = ei[N_EDGES + i];
        atomicAdd(&h[d >> 7], 1);
    }
    __syncthreads();
    for (int i = tid; i < NBKT; i += 256) {
        int c = h[i];
        if (c) atomicAdd(&bucket_cnt[i], c);
    }
}

__global__ __launch_bounds__(256) void bkt_scan_kernel(const int* __restrict__ bucket_cnt,
                                                       int* __restrict__ bucket_off, int* __restrict__ cursor) {
    __shared__ int ps[256];
    int tid = threadIdx.x;
    int base = tid * 4;
    int v[4];
    int s = 0;
    #pragma unroll
    for (int i = 0; i < 4; i++) {
        v[i] = (base + i < NBKT) ? bucket_cnt[base + i] : 0;
        s += v[i];
    }
    ps[tid] = s;
    __syncthreads();
    for (int off = 1; off < 256; off <<= 1) {
        int y = 0;
        if (tid >= off) y = ps[tid - off];
        __syncthreads();
        if (tid >= off) ps[tid] += y;
        __syncthreads();
    }
    int run = ps[tid] - s;   // exclusive
    #pragma unroll
    for (int i = 0; i < 4; i++) {
        if (base + i < NBKT) { bucket_off[base + i] = run; cursor[base + i] = run; }
        run += v[i];
    }
    if (tid == 0) bucket_off[NBKT] = N_EDGES;
}

__global__ __launch_bounds__(256) void bkt_scatter_kernel(const int* __restrict__ ei, int* __restrict__ cursor,
                                                          int2* __restrict__ pairs) {
    __shared__ int h[NBKT];
    __shared__ int basearr[NBKT];
    int tid = threadIdx.x;
    for (int i = tid; i < NBKT; i += 256) h[i] = 0;
    __syncthreads();
    int start = blockIdx.x * BKT_CHUNK;
    int end = start + BKT_CHUNK; if (end > N_EDGES) end = N_EDGES;
    for (int i = start + tid; i < end; i += 256) {
        int d = ei[N_EDGES + i];
        atomicAdd(&h[d >> 7], 1);
    }
    __syncthreads();
    for (int b = tid; b < NBKT; b += 256) {
        int c = h[b];
        basearr[b] = c ? atomicAdd(&cursor[b], c) : 0;
        h[b] = 0;
    }
    __syncthreads();
    for (int i = start + tid; i < end; i += 256) {
        int s = ei[i];
        int d = ei[N_EDGES + i];
        int bkt = d >> 7;
        int pos = basearr[bkt] + atomicAdd(&h[bkt], 1);
        pairs[pos] = make_int2(s, d);
    }
}

__global__ __launch_bounds__(256) void bkt_deg_kernel(const int2* __restrict__ pairs, const int* __restrict__ bucket_off,
                                                      int* __restrict__ deg) {
    __shared__ int c[128];
    int tid = threadIdx.x;
    if (tid < 128) c[tid] = 0;
    __syncthreads();
    int s0 = bucket_off[blockIdx.x], s1 = bucket_off[blockIdx.x + 1];
    for (int i = s0 + tid; i < s1; i += 256) {
        int d = pairs[i].y;
        atomicAdd(&c[d & 127], 1);
    }
    __syncthreads();
    int node = blockIdx.x * 128 + tid;
    if (tid < 128 && node < N_NODES) deg[node] = c[tid];
}

// CSR fill in SORTED space: position from row_ptr[rank[dst]], col value = rank[src]
__global__ __launch_bounds__(256) void bkt_fill_kernel(const int2* __restrict__ pairs, const int* __restrict__ bucket_off,
                                                       const int* __restrict__ row_ptr, const int* __restrict__ rank,
                                                       int* __restrict__ col) {
    __shared__ int rp[128];
    __shared__ int c[128];
    int tid = threadIdx.x;
    int node = blockIdx.x * 128 + tid;
    if (tid < 128) {
        rp[tid] = (node < N_NODES) ? row_ptr[rank[node]] : 0;
        c[tid] = 0;
    }
    __syncthreads();
    int s0 = bucket_off[blockIdx.x], s1 = bucket_off[blockIdx.x + 1];
    for (int i = s0 + tid; i < s1; i += 256) {
        int2 e = pairs[i];
        int dl = e.y & 127;
        int pos = rp[dl] + atomicAdd(&c[dl], 1);
        col[pos] = rank[e.x];
    }
}

// ---------------- degree counting sort (contention-free) ----------------
__global__ __launch_bounds__(256) void dsort_hist_kernel(const int* __restrict__ deg, int* __restrict__ bh) {
    __shared__ int h[64];
    int tid = threadIdx.x;
    if (tid < 64) h[tid] = 0;
    __syncthreads();
    int start = blockIdx.x * SORT_CHUNK;
    int end = start + SORT_CHUNK; if (end > N_NODES) end = N_NODES;
    for (int i = start + tid; i < end; i += 256) atomicAdd(&h[min(deg[i], 63)], 1);
    __syncthreads();
    if (tid < 64) bh[tid * SORT_BLOCKS + blockIdx.x] = h[tid];
}

__global__ __launch_bounds__(256) void dsort_scan_kernel(int* __restrict__ bh) {
    __shared__ int ps[256];
    int tid = threadIdx.x;
    int v[10];
    int s = 0;
    #pragma unroll
    for (int k = 0; k < 10; k++) { v[k] = bh[tid * 10 + k]; s += v[k]; }
    ps[tid] = s;
    __syncthreads();
    for (int off = 1; off < 256; off <<= 1) {
        int y = 0;
        if (tid >= off) y = ps[tid - off];
        __syncthreads();
        if (tid >= off) ps[tid] += y;
        __syncthreads();
    }
    int run = ps[tid] - s;
    #pragma unroll
    for (int k = 0; k < 10; k++) { int t = v[k]; bh[tid * 10 + k] = run; run += t; }
}

__global__ __launch_bounds__(256) void dsort_scat_kernel(const int* __restrict__ deg, const int* __restrict__ bh,
                                                         int* __restrict__ ord, int* __restrict__ rank,
                                                         int* __restrict__ deg_s) {
    __shared__ int h[64];
    __shared__ int base[64];
    int tid = threadIdx.x;
    if (tid < 64) { h[tid] = 0; base[tid] = bh[tid * SORT_BLOCKS + blockIdx.x]; }
    __syncthreads();
    int start = blockIdx.x * SORT_CHUNK;
    int end = start + SORT_CHUNK; if (end > N_NODES) end = N_NODES;
    for (int i = start + tid; i < end; i += 256) {
        int d = deg[i];
        int b = min(d, 63);
        int pos = base[b] + atomicAdd(&h[b], 1);
        ord[pos] = i;
        rank[i] = pos;
        deg_s[pos] = d;
    }
}

// ---------------- scan of deg_s -> row_ptr (sorted space) ----------------
#define SCAN_ELEMS 1024
__global__ __launch_bounds__(256) void scan_a_kernel(const int* __restrict__ deg, int* __restrict__ bsum) {
    __shared__ int lds[256];
    int tid = threadIdx.x;
    int base = blockIdx.x * SCAN_ELEMS + tid * 4;
    int s = 0;
    #pragma unroll
    for (int i = 0; i < 4; i++) {
        int idx = base + i;
        s += (idx < N_NODES) ? deg[idx] : 0;
    }
    lds[tid] = s;
    __syncthreads();
    for (int off = 128; off; off >>= 1) {
        if (tid < off) lds[tid] += lds[tid + off];
        __syncthreads();
    }
    if (tid == 0) bsum[blockIdx.x] = lds[0];
}

__global__ void scan_b_kernel(int* __restrict__ bsum, int nb) {
    if (threadIdx.x == 0 && blockIdx.x == 0) {
        int acc = 0;
        for (int i = 0; i < nb; i++) { int v = bsum[i]; bsum[i] = acc; acc += v; }
    }
}

__global__ __launch_bounds__(256) void scan_c_kernel(const int* __restrict__ deg, const int* __restrict__ bsum,
                                                     int* __restrict__ row_ptr) {
    __shared__ int lds[256];
    int tid = threadIdx.x;
    int base = blockIdx.x * SCAN_ELEMS + tid * 4;
    int v[4];
    int s = 0;
    #pragma unroll
    for (int i = 0; i < 4; i++) {
        int idx = base + i;
        v[i] = (idx < N_NODES) ? deg[idx] : 0;
        s += v[i];
    }
    lds[tid] = s;
    __syncthreads();
    for (int off = 1; off < 256; off <<= 1) {
        int y = 0;
        if (tid >= off) y = lds[tid - off];
        __syncthreads();
        if (tid >= off) lds[tid] += y;
        __syncthreads();
    }
    int run = bsum[blockIdx.x] + lds[tid] - s;
    #pragma unroll
    for (int i = 0; i < 4; i++) {
        int idx = base + i;
        if (idx < N_NODES) row_ptr[idx] = run;
        run += v[i];
    }
    if (blockIdx.x == 0 && tid == 0) row_ptr[N_NODES] = N_EDGES;
}

// ---------------- x (fp32, orig space) -> xcat[:,0:64] bf16 at rank[node], ld 128 ----------------
__global__ __launch_bounds__(256) void xbf_kernel(const float* __restrict__ x, const int* __restrict__ rank,
                                                  unsigned short* __restrict__ xcat) {
    int idx = blockIdx.x * 256 + threadIdx.x;   // one float4 per thread
    if (idx < N_NODES * 16) {
        int node = idx >> 4;
        int f0 = (idx & 15) * 4;
        int rn = rank[node];
        float4 v = *(const float4*)(x + (size_t)idx * 4);
        ushort4 o;
        o.x = f2bf(v.x); o.y = f2bf(v.y); o.z = f2bf(v.z); o.w = f2bf(v.w);
        *(ushort4*)(xcat + (size_t)rn * 128 + f0) = o;
    }
}

// ---------------- layer-1 agg: mean of xcat[j,0:64] -> xcat[i,64:128]; 16 lanes/node ----------------
__global__ __launch_bounds__(256) void agg64_kernel(unsigned short* __restrict__ xcat,
                                                    const int* __restrict__ row_ptr, const int* __restrict__ col) {
    int tid = threadIdx.x;
    int i = blockIdx.x * 16 + (tid >> 4);
    if (i >= N_NODES) return;
    int f0 = (tid & 15) * 4;
    int s = row_ptr[i], e = row_ptr[i + 1];
    float a0 = 0.f, a1 = 0.f, a2 = 0.f, a3 = 0.f;
    int t = s;
    for (; t + 1 < e; t += 2) {
        int j0 = col[t], j1 = col[t + 1];
        ushort4 u = *(const ushort4*)(xcat + (size_t)j0 * 128 + f0);
        ushort4 v = *(const ushort4*)(xcat + (size_t)j1 * 128 + f0);
        a0 += bf2f(u.x) + bf2f(v.x);
        a1 += bf2f(u.y) + bf2f(v.y);
        a2 += bf2f(u.z) + bf2f(v.z);
        a3 += bf2f(u.w) + bf2f(v.w);
    }
    if (t < e) {
        ushort4 u = *(const ushort4*)(xcat + (size_t)col[t] * 128 + f0);
        a0 += bf2f(u.x); a1 += bf2f(u.y); a2 += bf2f(u.z); a3 += bf2f(u.w);
    }
    float di = 1.0f / fmaxf((float)(e - s), 1.0f);
    ushort4 o;
    o.x = f2bf(a0 * di); o.y = f2bf(a1 * di); o.z = f2bf(a2 * di); o.w = f2bf(a3 * di);
    *(ushort4*)(xcat + (size_t)i * 128 + 64 + f0) = o;
}

// ---------------- layers 2/3 agg: mean of hcat[j,0:128] -> hcat[i,128:256]; 32 lanes/node ----------------
__global__ __launch_bounds__(256) void agg128_kernel(unsigned short* __restrict__ hcat,
                                                     const int* __restrict__ row_ptr, const int* __restrict__ col) {
    int tid = threadIdx.x;
    int i = blockIdx.x * 8 + (tid >> 5);
    if (i >= N_NODES) return;
    int f0 = (tid & 31) * 4;
    int s = row_ptr[i], e = row_ptr[i + 1];
    float a0 = 0.f, a1 = 0.f, a2 = 0.f, a3 = 0.f;
    int t = s;
    for (; t + 1 < e; t += 2) {
        int j0 = col[t], j1 = col[t + 1];
        ushort4 u = *(const ushort4*)(hcat + (size_t)j0 * 256 + f0);
        ushort4 v = *(const ushort4*)(hcat + (size_t)j1 * 256 + f0);
        a0 += bf2f(u.x) + bf2f(v.x);
        a1 += bf2f(u.y) + bf2f(v.y);
        a2 += bf2f(u.z) + bf2f(v.z);
        a3 += bf2f(u.w) + bf2f(v.w);
    }
    if (t < e) {
        ushort4 u = *(const ushort4*)(hcat + (size_t)col[t] * 256 + f0);
        a0 += bf2f(u.x); a1 += bf2f(u.y); a2 += bf2f(u.z); a3 += bf2f(u.w);
    }
    float di = 1.0f / fmaxf((float)(e - s), 1.0f);
    ushort4 o;
    o.x = f2bf(a0 * di); o.y = f2bf(a1 * di); o.z = f2bf(a2 * di); o.w = f2bf(a3 * di);
    *(ushort4*)(hcat + (size_t)i * 256 + 128 + f0) = o;
}

// ---------------- weight prep (transposed bf16) ----------------
// layer1: A = [x(k<64) | aggx(k>=64)], Bt1[n][k], n in [0,256), k in [0,128)
__global__ __launch_bounds__(256) void wprep1_kernel(const float* __restrict__ Wr1, const float* __restrict__ Wl1,
                                                     const float* __restrict__ Wres, unsigned short* __restrict__ Bt) {
    int idx = blockIdx.x * 256 + threadIdx.x;   // n*128 + k
    if (idx >= 256 * 128) return;
    int n = idx >> 7;
    int k = idx & 127;
    float v;
    if (n < 128) v = (k < 64) ? Wr1[k * 128 + n] : Wl1[(k - 64) * 128 + n];
    else         v = (k < 64) ? Wres[k * 128 + (n - 128)] : 0.f;
    Bt[idx] = f2bf(v);
}

// layers 2/3: A = [h(k<128) | aggh(k>=128)], Bt[n][k] = k<128 ? Wr[k][n] : Wl[k-128][n]
__global__ __launch_bounds__(256) void wprep23_kernel(const float* __restrict__ Wl, const float* __restrict__ Wr,
                                                      unsigned short* __restrict__ Bt) {
    int idx = blockIdx.x * 256 + threadIdx.x;   // n*256 + k
    if (idx >= 128 * 256) return;
    int n = idx >> 8;
    int k = idx & 255;
    float v = (k < 128) ? Wr[k * 128 + n] : Wl[(k - 128) * 128 + n];
    Bt[idx] = f2bf(v);
}

// ---------------- MFMA bf16 GEMM: C[M x ...] = A[M x lda] @ Bt^T, row-major bf16 ----------------
// Bt is [Nout][lda]. Out col = n0 + local, written bf16 to C + m*ldc + col.
// bias != null -> +bias[col], relu. In-place over A (layers 2/3) is safe: single
// n-tile, each block writes only rows it alone reads, after all its reads.
__global__ __launch_bounds__(256) void mgemm_kernel(const unsigned short* __restrict__ A, int lda,
                                                    const unsigned short* __restrict__ Bt, int M,
                                                    const float* __restrict__ bias,
                                                    unsigned short* __restrict__ C, int ldc) {
    __shared__ unsigned short As[128 * LP];
    __shared__ unsigned short Bs[128 * LP];
    int tid = threadIdx.x;
    int m0 = blockIdx.x * 128;
    int n0 = blockIdx.y * 128;

    int lane = tid & 63;
    int wave = tid >> 6;
    int wm = (wave & 1) * 64;
    int wn = (wave >> 1) * 64;
    int lm = lane & 15;
    int lk = (lane >> 4) * 8;

    float4v acc[4][4];
    #pragma unroll
    for (int i = 0; i < 4; i++)
        #pragma unroll
        for (int j = 0; j < 4; j++) acc[i][j] = (float4v)0.f;

    int sr = tid >> 3;          // staging row 0..31
    int sc = (tid & 7) * 8;     // staging col (shorts)

    for (int ks = 0; ks < lda; ks += 64) {
        if (ks) __syncthreads();
        int kk = ks + sc;
        #pragma unroll
        for (int rr = 0; rr < 128; rr += 32) {
            int r = sr + rr;
            int gm = m0 + r; if (gm > M - 1) gm = M - 1;
            ulonglong2 va = *(const ulonglong2*)(A + (size_t)gm * lda + kk);
            *(ulonglong2*)&As[r * LP + sc] = va;
            ulonglong2 vb = *(const ulonglong2*)(Bt + (size_t)(n0 + r) * lda + kk);
            *(ulonglong2*)&Bs[r * LP + sc] = vb;
        }
        __syncthreads();

        #pragma unroll
        for (int k0 = 0; k0 < 64; k0 += 32) {
            short8v af[4], bf[4];
            #pragma unroll
            for (int i = 0; i < 4; i++)
                af[i] = *(const short8v*)&As[(wm + i * 16 + lm) * LP + k0 + lk];
            #pragma unroll
            for (int j = 0; j < 4; j++)
                bf[j] = *(const short8v*)&Bs[(wn + j * 16 + lm) * LP + k0 + lk];
            #pragma unroll
            for (int i = 0; i < 4; i++)
                #pragma unroll
                for (int j = 0; j < 4; j++)
                    acc[i][j] = __builtin_amdgcn_mfma_f32_16x16x32_bf16(af[i], bf[j], acc[i][j], 0, 0, 0);
        }
    }

    int r0b = (lane >> 4) * 4;
    #pragma unroll
    for (int i = 0; i < 4; i++) {
        #pragma unroll
        for (int j = 0; j < 4; j++) {
            int cc = n0 + wn + j * 16 + (lane & 15);
            float bv = (bias != nullptr) ? bias[cc] : 0.f;
            #pragma unroll
            for (int r = 0; r < 4; r++) {
                int m = m0 + wm + i * 16 + r0b + r;
                if (m < M) {
                    float v = acc[i][j][r];
                    if (bias != nullptr) v = fmaxf(v + bv, 0.f);
                    C[(size_t)m * ldc + cc] = f2bf(v);
                }
            }
        }
    }
}

// ---------------- layer1 epilogue: t=Ub[:,0:128]+b1 -> LN -> relu -> + Ub[:,128:256]+bres ----------------
__global__ __launch_bounds__(256) void ln_kernel(const unsigned short* __restrict__ Ub, const float* __restrict__ b1,
                                                 const float* __restrict__ ln_g, const float* __restrict__ ln_b,
                                                 const float* __restrict__ bres, unsigned short* __restrict__ hcat) {
    int tid = threadIdx.x;
    int grp = tid >> 7;
    int f = tid & 127;
    int i = blockIdx.x * 2 + grp;
    bool valid = i < N_NODES;
    float t = 0.f;
    if (valid) t = bf2f(Ub[(size_t)i * 256 + f]) + b1[f];
    float s = t, s2 = t * t;
    #pragma unroll
    for (int off = 32; off; off >>= 1) {
        s += __shfl_down(s, off);
        s2 += __shfl_down(s2, off);
    }
    __shared__ float rs[4], rs2[4];
    int wave = tid >> 6;
    if ((tid & 63) == 0) { rs[wave] = s; rs2[wave] = s2; }
    __syncthreads();
    float sum = rs[grp * 2] + rs[grp * 2 + 1];
    float sumsq = rs2[grp * 2] + rs2[grp * 2 + 1];
    float mu = sum * (1.f / 128.f);
    float var = sumsq * (1.f / 128.f) - mu * mu;
    float r = rsqrtf(var + 1e-5f);
    if (valid) {
        float y = (t - mu) * r * ln_g[f] + ln_b[f];
        y = fmaxf(y, 0.f);
        y += bf2f(Ub[(size_t)i * 256 + 128 + f]) + bres[f];
        hcat[(size_t)i * 256 + f] = f2bf(y);
    }
}

// ---------------- layer4 (sorted space) ----------------
__global__ __launch_bounds__(256) void pq_kernel(const unsigned short* __restrict__ hcat, const float* __restrict__ Wl4,
                                                 const float* __restrict__ Wr4, const float* __restrict__ b4,
                                                 float* __restrict__ p, float* __restrict__ q) {
    int tid = threadIdx.x;
    int lane = tid & 63;
    int w = tid >> 6;
    int i = blockIdx.x * 4 + w;
    if (i >= N_NODES) return;
    const unsigned short* hr = hcat + (size_t)i * 256;
    float a = bf2f(hr[lane]), b = bf2f(hr[64 + lane]);
    float pp = a * Wl4[lane] + b * Wl4[64 + lane];
    float qq = a * Wr4[lane] + b * Wr4[64 + lane];
    #pragma unroll
    for (int off = 32; off; off >>= 1) {
        pp += __shfl_down(pp, off);
        qq += __shfl_down(qq, off);
    }
    if (lane == 0) { p[i] = pp; q[i] = qq + b4[0]; }
}

__global__ __launch_bounds__(256) void final_kernel(const float* __restrict__ p, const float* __restrict__ q,
                                                    const int* __restrict__ row_ptr, const int* __restrict__ col,
                                                    const int* __restrict__ ord, float* __restrict__ out) {
    int i = blockIdx.x * 256 + threadIdx.x;   // sorted slot
    if (i >= N_NODES) return;
    int s = row_ptr[i], e = row_ptr[i + 1];
    float acc = 0.f;
    for (int t = s; t < e; t++) acc += p[col[t]];
    float di = 1.0f / fmaxf((float)(e - s), 1.0f);
    out[ord[i]] = acc * di + q[i];
}

// ---------------- launch ----------------

extern "C" void kernel_launch(void* const* d_in, const int* in_sizes, int n_in,
                              void* d_out, int out_size, void* d_ws, size_t ws_size,
                              hipStream_t stream) {
    const float* x    = (const float*)d_in[0];
    const int*   ei   = (const int*)d_in[1];
    const float* Wl1  = (const float*)d_in[2];
    const float* Wr1  = (const float*)d_in[3];
    const float* b1   = (const float*)d_in[4];
    const float* ln_g = (const float*)d_in[5];
    const float* ln_b = (const float*)d_in[6];
    const float* Wres = (const float*)d_in[7];
    const float* bres = (const float*)d_in[8];
    const float* Wl2  = (const float*)d_in[9];
    const float* Wr2  = (const float*)d_in[10];
    const float* b2   = (const float*)d_in[11];
    const float* Wl3  = (const float*)d_in[12];
    const float* Wr3  = (const float*)d_in[13];
    const float* b3   = (const float*)d_in[14];
    const float* Wl4  = (const float*)d_in[15];
    const float* Wr4  = (const float*)d_in[16];
    const float* b4   = (const float*)d_in[17];
    float* out = (float*)d_out;

    char* w = (char*)d_ws;
    size_t off = 0;
    auto alloc = [&](size_t bytes) -> void* {
        off = (off + 255) & ~(size_t)255;
        void* pp = w + off;
        off += bytes;
        return pp;
    };

    int*   deg        = (int*)alloc(N_NODES * 4);       // original space
    int*   deg_s      = (int*)alloc(N_NODES * 4);       // sorted space
    int*   row_ptr    = (int*)alloc((N_NODES + 1) * 4); // sorted space
    int*   bsum       = (int*)alloc(512);
    int*   col        = (int*)alloc(N_EDGES * 4);       // sorted-space src ids
    int*   bucket_cnt = (int*)alloc(NBKT * 4);
    int*   bucket_off = (int*)alloc((NBKT + 1) * 4);
    int*   cursor     = (int*)alloc(NBKT * 4);
    int*   bh         = (int*)alloc(64 * SORT_BLOCKS * 4);
    int*   ord        = (int*)alloc(N_NODES * 4);       // slot -> orig
    int*   rank       = (int*)alloc(N_NODES * 4);       // orig -> slot
    unsigned short* Btw  = (unsigned short*)alloc(128 * 256 * 2);
    unsigned short* xcat = (unsigned short*)alloc((size_t)N_NODES * 128 * 2);  // [x | aggx] bf16
    unsigned short* hcat = (unsigned short*)alloc((size_t)N_NODES * 256 * 2);  // [h | aggh] bf16
    float* U       = (float*)alloc((size_t)N_NODES * 256 * 4);   // scratch: pairs, then Ub
    float* p       = (float*)alloc(N_NODES * 4);
    float* q       = (float*)alloc(N_NODES * 4);
    int2* pairs = (int2*)U;                  // CSR build scratch (done before U reused)
    unsigned short* Ub = (unsigned short*)U; // layer-1 GEMM out, N x 256 bf16 row-major
    (void)ws_size; (void)n_in; (void)in_sizes; (void)out_size;

    const int NB = (N_NODES + 255) / 256;
    const int SCB = (N_NODES + SCAN_ELEMS - 1) / SCAN_ELEMS;
    const int MB = (N_NODES + 127) / 128;   // 782

    // --- CSR build (dst-bucket sort; fill into degree-sorted node space) ---
    hipMemsetAsync(bucket_cnt, 0, NBKT * 4, stream);
    bkt_count_kernel<<<SCAT_BLOCKS, 256, 0, stream>>>(ei, bucket_cnt);
    bkt_scan_kernel<<<1, 256, 0, stream>>>(bucket_cnt, bucket_off, cursor);
    bkt_scatter_kernel<<<SCAT_BLOCKS, 256, 0, stream>>>(ei, cursor, pairs);
    bkt_deg_kernel<<<NBKT, 256, 0, stream>>>(pairs, bucket_off, deg);
    dsort_hist_kernel<<<SORT_BLOCKS, 256, 0, stream>>>(deg, bh);
    dsort_scan_kernel<<<1, 256, 0, stream>>>(bh);
    dsort_scat_kernel<<<SORT_BLOCKS, 256, 0, stream>>>(deg, bh, ord, rank, deg_s);
    scan_a_kernel<<<SCB, 256, 0, stream>>>(deg_s, bsum);
    scan_b_kernel<<<1, 64, 0, stream>>>(bsum, SCB);
    scan_c_kernel<<<SCB, 256, 0, stream>>>(deg_s, bsum, row_ptr);
    bkt_fill_kernel<<<NBKT, 256, 0, stream>>>(pairs, bucket_off, row_ptr, rank, col);

    // --- layer 1: xcat = [x | mean-agg(x)] bf16 (sorted space); GEMM -> Ub; LN -> hcat[:,0:128] ---
    xbf_kernel<<<(N_NODES * 16 + 255) / 256, 256, 0, stream>>>(x, rank, xcat);
    agg64_kernel<<<(N_NODES + 15) / 16, 256, 0, stream>>>(xcat, row_ptr, col);
    wprep1_kernel<<<128, 256, 0, stream>>>(Wr1, Wl1, Wres, Btw);
    mgemm_kernel<<<dim3(MB, 2), 256, 0, stream>>>(xcat, 128, Btw, N_NODES, nullptr, Ub, 256);
    ln_kernel<<<(N_NODES + 1) / 2, 256, 0, stream>>>(Ub, b1, ln_g, ln_b, bres, hcat);

    // --- layer 2: agg(h) -> hcat[:,128:256]; GEMM [h|aggh] -> hcat[:,0:128] (bias+relu) ---
    agg128_kernel<<<(N_NODES + 7) / 8, 256, 0, stream>>>(hcat, row_ptr, col);
    wprep23_kernel<<<128, 256, 0, stream>>>(Wl2, Wr2, Btw);
    mgemm_kernel<<<dim3(MB, 1), 256, 0, stream>>>(hcat, 256, Btw, N_NODES, b2, hcat, 256);

    // --- layer 3 ---
    agg128_kernel<<<(N_NODES + 7) / 8, 256, 0, stream>>>(hcat, row_ptr, col);
    wprep23_kernel<<<128, 256, 0, stream>>>(Wl3, Wr3, Btw);
    mgemm_kernel<<<dim3(MB, 1), 256, 0, stream>>>(hcat, 256, Btw, N_NODES, b3, hcat, 256);

    // --- layer 4 ---
    pq_kernel<<<(N_NODES + 3) / 4, 256, 0, stream>>>(hcat, Wl4, Wr4, b4, p, q);
    final_kernel<<<NB, 256, 0, stream>>>(p, q, row_ptr, col, ord, out);
}

// Round 9
// 526.748 us; speedup vs baseline: 2.5540x; 1.0333x over previous
//
#include <hip/hip_runtime.h>
#include <hip/hip_bf16.h>

#define N_NODES 100000
#define N_EDGES 1600000

#define NBKT 782                 // ceil(N_NODES / 128)
#define BKT_CHUNK 13334          // ceil(N_EDGES / 120)
#define SCAT_BLOCKS 120
#define LP 72                    // padded LDS row length in shorts (64 + 8)

#define SORT_BLOCKS 40
#define SORT_CHUNK 2500          // 40 * 2500 = 100000
#define BH2_N (NBKT * SCAT_BLOCKS)   // 93840

typedef __attribute__((ext_vector_type(8))) short short8v;
typedef __attribute__((ext_vector_type(4))) float float4v;

__device__ __forceinline__ unsigned short f2bf(float f) {
    unsigned int u = __float_as_uint(f);
    u = (u + 0x7FFFu + ((u >> 16) & 1u)) >> 16;   // RTNE
    return (unsigned short)u;
}
__device__ __forceinline__ float bf2f(unsigned short b) {
    return __uint_as_float((unsigned int)b << 16);
}

// ---------------- CSR build: one histogram pass + big scan + one-pass scatter ----------------
// bucket b = dst >> 7. bh2[b * SCAT_BLOCKS + blk] = count of bucket-b edges in block blk's
// chunk; after exclusive scan (bucket-major) it is the exact base for (b, blk).

__global__ __launch_bounds__(256) void bkt_hist_kernel(const int* __restrict__ ei, int* __restrict__ bh2) {
    __shared__ int h[NBKT];
    int tid = threadIdx.x;
    for (int i = tid; i < NBKT; i += 256) h[i] = 0;
    __syncthreads();
    int start = blockIdx.x * BKT_CHUNK;
    int end = start + BKT_CHUNK; if (end > N_EDGES) end = N_EDGES;
    for (int i = start + tid; i < end; i += 256) {
        int d = ei[N_EDGES + i];
        atomicAdd(&h[d >> 7], 1);
    }
    __syncthreads();
    for (int i = tid; i < NBKT; i += 256) bh2[i * SCAT_BLOCKS + blockIdx.x] = h[i];
}

// generic block-sum (1024 elems/block)
__global__ __launch_bounds__(256) void gscan_a_kernel(const int* __restrict__ in, int* __restrict__ bsum, int n) {
    __shared__ int lds[256];
    int tid = threadIdx.x;
    int base = blockIdx.x * 1024 + tid * 4;
    int s = 0;
    #pragma unroll
    for (int i = 0; i < 4; i++) s += (base + i < n) ? in[base + i] : 0;
    lds[tid] = s;
    __syncthreads();
    for (int off = 128; off; off >>= 1) {
        if (tid < off) lds[tid] += lds[tid + off];
        __syncthreads();
    }
    if (tid == 0) bsum[blockIdx.x] = lds[0];
}

__global__ void scan_b_kernel(int* __restrict__ bsum, int nb) {
    if (threadIdx.x == 0 && blockIdx.x == 0) {
        int acc = 0;
        for (int i = 0; i < nb; i++) { int v = bsum[i]; bsum[i] = acc; acc += v; }
    }
}

// generic in-place exclusive scan apply
__global__ __launch_bounds__(256) void gscan_c_kernel(int* __restrict__ data, const int* __restrict__ bsum, int n) {
    __shared__ int lds[256];
    int tid = threadIdx.x;
    int base = blockIdx.x * 1024 + tid * 4;
    int v[4];
    int s = 0;
    #pragma unroll
    for (int i = 0; i < 4; i++) {
        v[i] = (base + i < n) ? data[base + i] : 0;
        s += v[i];
    }
    lds[tid] = s;
    __syncthreads();
    for (int off = 1; off < 256; off <<= 1) {
        int y = 0;
        if (tid >= off) y = lds[tid - off];
        __syncthreads();
        if (tid >= off) lds[tid] += y;
        __syncthreads();
    }
    int run = bsum[blockIdx.x] + lds[tid] - s;
    #pragma unroll
    for (int i = 0; i < 4; i++) {
        if (base + i < n) data[base + i] = run;
        run += v[i];
    }
}

__global__ __launch_bounds__(256) void extract_off_kernel(const int* __restrict__ bh2, int* __restrict__ bucket_off) {
    int i = blockIdx.x * 256 + threadIdx.x;
    if (i < NBKT) bucket_off[i] = bh2[i * SCAT_BLOCKS];
    if (i == NBKT) bucket_off[NBKT] = N_EDGES;
}

// one-pass scatter: base from scanned bh2, local rank via LDS atomics; packed (src<<7)|(dst&127)
__global__ __launch_bounds__(256) void bkt_scatter2_kernel(const int* __restrict__ ei, const int* __restrict__ bh2,
                                                           int* __restrict__ packed) {
    __shared__ int h[NBKT];
    __shared__ int base[NBKT];
    int tid = threadIdx.x;
    for (int i = tid; i < NBKT; i += 256) { h[i] = 0; base[i] = bh2[i * SCAT_BLOCKS + blockIdx.x]; }
    __syncthreads();
    int start = blockIdx.x * BKT_CHUNK;
    int end = start + BKT_CHUNK; if (end > N_EDGES) end = N_EDGES;
    for (int i = start + tid; i < end; i += 256) {
        int s = ei[i];
        int d = ei[N_EDGES + i];
        int b = d >> 7;
        int pos = base[b] + atomicAdd(&h[b], 1);
        packed[pos] = (s << 7) | (d & 127);
    }
}

__global__ __launch_bounds__(256) void bkt_deg2_kernel(const int* __restrict__ packed, const int* __restrict__ bucket_off,
                                                       int* __restrict__ deg) {
    __shared__ int c[128];
    int tid = threadIdx.x;
    if (tid < 128) c[tid] = 0;
    __syncthreads();
    int s0 = bucket_off[blockIdx.x], s1 = bucket_off[blockIdx.x + 1];
    for (int i = s0 + tid; i < s1; i += 256) atomicAdd(&c[packed[i] & 127], 1);
    __syncthreads();
    int node = blockIdx.x * 128 + tid;
    if (tid < 128 && node < N_NODES) deg[node] = c[tid];
}

// CSR fill in SORTED space: position from row_ptr[rank[dst]], col value = rank[src]
__global__ __launch_bounds__(256) void bkt_fill2_kernel(const int* __restrict__ packed, const int* __restrict__ bucket_off,
                                                        const int* __restrict__ row_ptr, const int* __restrict__ rank,
                                                        int* __restrict__ col) {
    __shared__ int rp[128];
    __shared__ int c[128];
    int tid = threadIdx.x;
    int node = blockIdx.x * 128 + tid;
    if (tid < 128) {
        rp[tid] = (node < N_NODES) ? row_ptr[rank[node]] : 0;
        c[tid] = 0;
    }
    __syncthreads();
    int s0 = bucket_off[blockIdx.x], s1 = bucket_off[blockIdx.x + 1];
    for (int i = s0 + tid; i < s1; i += 256) {
        int p = packed[i];
        int dl = p & 127;
        int pos = rp[dl] + atomicAdd(&c[dl], 1);
        col[pos] = rank[p >> 7];
    }
}

// ---------------- degree counting sort (contention-free) ----------------
__global__ __launch_bounds__(256) void dsort_hist_kernel(const int* __restrict__ deg, int* __restrict__ bh) {
    __shared__ int h[64];
    int tid = threadIdx.x;
    if (tid < 64) h[tid] = 0;
    __syncthreads();
    int start = blockIdx.x * SORT_CHUNK;
    int end = start + SORT_CHUNK; if (end > N_NODES) end = N_NODES;
    for (int i = start + tid; i < end; i += 256) atomicAdd(&h[min(deg[i], 63)], 1);
    __syncthreads();
    if (tid < 64) bh[tid * SORT_BLOCKS + blockIdx.x] = h[tid];
}

__global__ __launch_bounds__(256) void dsort_scan_kernel(int* __restrict__ bh) {
    __shared__ int ps[256];
    int tid = threadIdx.x;
    int v[10];
    int s = 0;
    #pragma unroll
    for (int k = 0; k < 10; k++) { v[k] = bh[tid * 10 + k]; s += v[k]; }
    ps[tid] = s;
    __syncthreads();
    for (int off = 1; off < 256; off <<= 1) {
        int y = 0;
        if (tid >= off) y = ps[tid - off];
        __syncthreads();
        if (tid >= off) ps[tid] += y;
        __syncthreads();
    }
    int run = ps[tid] - s;
    #pragma unroll
    for (int k = 0; k < 10; k++) { int t = v[k]; bh[tid * 10 + k] = run; run += t; }
}

__global__ __launch_bounds__(256) void dsort_scat_kernel(const int* __restrict__ deg, const int* __restrict__ bh,
                                                         int* __restrict__ ord, int* __restrict__ rank,
                                                         int* __restrict__ deg_s) {
    __shared__ int h[64];
    __shared__ int base[64];
    int tid = threadIdx.x;
    if (tid < 64) { h[tid] = 0; base[tid] = bh[tid * SORT_BLOCKS + blockIdx.x]; }
    __syncthreads();
    int start = blockIdx.x * SORT_CHUNK;
    int end = start + SORT_CHUNK; if (end > N_NODES) end = N_NODES;
    for (int i = start + tid; i < end; i += 256) {
        int d = deg[i];
        int b = min(d, 63);
        int pos = base[b] + atomicAdd(&h[b], 1);
        ord[pos] = i;
        rank[i] = pos;
        deg_s[pos] = d;
    }
}

// ---------------- scan of deg_s -> row_ptr (sorted space, with sentinel) ----------------
__global__ __launch_bounds__(256) void scan_c_row_kernel(const int* __restrict__ deg, const int* __restrict__ bsum,
                                                         int* __restrict__ row_ptr) {
    __shared__ int lds[256];
    int tid = threadIdx.x;
    int base = blockIdx.x * 1024 + tid * 4;
    int v[4];
    int s = 0;
    #pragma unroll
    for (int i = 0; i < 4; i++) {
        int idx = base + i;
        v[i] = (idx < N_NODES) ? deg[idx] : 0;
        s += v[i];
    }
    lds[tid] = s;
    __syncthreads();
    for (int off = 1; off < 256; off <<= 1) {
        int y = 0;
        if (tid >= off) y = lds[tid - off];
        __syncthreads();
        if (tid >= off) lds[tid] += y;
        __syncthreads();
    }
    int run = bsum[blockIdx.x] + lds[tid] - s;
    #pragma unroll
    for (int i = 0; i < 4; i++) {
        int idx = base + i;
        if (idx < N_NODES) row_ptr[idx] = run;
        run += v[i];
    }
    if (blockIdx.x == 0 && tid == 0) row_ptr[N_NODES] = N_EDGES;
}

// ---------------- x (fp32, orig space) -> xcat[:,0:64] bf16 at rank[node], ld 128 ----------------
__global__ __launch_bounds__(256) void xbf_kernel(const float* __restrict__ x, const int* __restrict__ rank,
                                                  unsigned short* __restrict__ xcat) {
    int idx = blockIdx.x * 256 + threadIdx.x;   // one float4 per thread
    if (idx < N_NODES * 16) {
        int node = idx >> 4;
        int f0 = (idx & 15) * 4;
        int rn = rank[node];
        float4 v = *(const float4*)(x + (size_t)idx * 4);
        ushort4 o;
        o.x = f2bf(v.x); o.y = f2bf(v.y); o.z = f2bf(v.z); o.w = f2bf(v.w);
        *(ushort4*)(xcat + (size_t)rn * 128 + f0) = o;
    }
}

#define ACC4(u) { a0 += bf2f(u.x); a1 += bf2f(u.y); a2 += bf2f(u.z); a3 += bf2f(u.w); }

// ---------------- layer-1 agg: mean of xcat[j,0:64] -> xcat[i,64:128]; 16 lanes/node ----------------
// Tiered 8/4/2/1 unroll: latency-bound gather needs many independent loads in flight.
__global__ __launch_bounds__(256) void agg64_kernel(unsigned short* __restrict__ xcat,
                                                    const int* __restrict__ row_ptr, const int* __restrict__ col) {
    int tid = threadIdx.x;
    int i = blockIdx.x * 16 + (tid >> 4);
    if (i >= N_NODES) return;
    int f0 = (tid & 15) * 4;
    int s = row_ptr[i], e = row_ptr[i + 1];
    float a0 = 0.f, a1 = 0.f, a2 = 0.f, a3 = 0.f;
    int t = s;
    while (t + 7 < e) {
        int j0 = col[t], j1 = col[t + 1], j2 = col[t + 2], j3 = col[t + 3];
        int j4 = col[t + 4], j5 = col[t + 5], j6 = col[t + 6], j7 = col[t + 7];
        ushort4 u0 = *(const ushort4*)(xcat + (size_t)j0 * 128 + f0);
        ushort4 u1 = *(const ushort4*)(xcat + (size_t)j1 * 128 + f0);
        ushort4 u2 = *(const ushort4*)(xcat + (size_t)j2 * 128 + f0);
        ushort4 u3 = *(const ushort4*)(xcat + (size_t)j3 * 128 + f0);
        ushort4 u4 = *(const ushort4*)(xcat + (size_t)j4 * 128 + f0);
        ushort4 u5 = *(const ushort4*)(xcat + (size_t)j5 * 128 + f0);
        ushort4 u6 = *(const ushort4*)(xcat + (size_t)j6 * 128 + f0);
        ushort4 u7 = *(const ushort4*)(xcat + (size_t)j7 * 128 + f0);
        ACC4(u0) ACC4(u1) ACC4(u2) ACC4(u3) ACC4(u4) ACC4(u5) ACC4(u6) ACC4(u7)
        t += 8;
    }
    if (t + 3 < e) {
        int j0 = col[t], j1 = col[t + 1], j2 = col[t + 2], j3 = col[t + 3];
        ushort4 u0 = *(const ushort4*)(xcat + (size_t)j0 * 128 + f0);
        ushort4 u1 = *(const ushort4*)(xcat + (size_t)j1 * 128 + f0);
        ushort4 u2 = *(const ushort4*)(xcat + (size_t)j2 * 128 + f0);
        ushort4 u3 = *(const ushort4*)(xcat + (size_t)j3 * 128 + f0);
        ACC4(u0) ACC4(u1) ACC4(u2) ACC4(u3)
        t += 4;
    }
    if (t + 1 < e) {
        int j0 = col[t], j1 = col[t + 1];
        ushort4 u0 = *(const ushort4*)(xcat + (size_t)j0 * 128 + f0);
        ushort4 u1 = *(const ushort4*)(xcat + (size_t)j1 * 128 + f0);
        ACC4(u0) ACC4(u1)
        t += 2;
    }
    if (t < e) {
        ushort4 u0 = *(const ushort4*)(xcat + (size_t)col[t] * 128 + f0);
        ACC4(u0)
    }
    float di = 1.0f / fmaxf((float)(e - s), 1.0f);
    ushort4 o;
    o.x = f2bf(a0 * di); o.y = f2bf(a1 * di); o.z = f2bf(a2 * di); o.w = f2bf(a3 * di);
    *(ushort4*)(xcat + (size_t)i * 128 + 64 + f0) = o;
}

// ---------------- layers 2/3 agg: mean of hcat[j,0:128] -> hcat[i,128:256]; 32 lanes/node ----------------
__global__ __launch_bounds__(256) void agg128_kernel(unsigned short* __restrict__ hcat,
                                                     const int* __restrict__ row_ptr, const int* __restrict__ col) {
    int tid = threadIdx.x;
    int i = blockIdx.x * 8 + (tid >> 5);
    if (i >= N_NODES) return;
    int f0 = (tid & 31) * 4;
    int s = row_ptr[i], e = row_ptr[i + 1];
    float a0 = 0.f, a1 = 0.f, a2 = 0.f, a3 = 0.f;
    int t = s;
    while (t + 7 < e) {
        int j0 = col[t], j1 = col[t + 1], j2 = col[t + 2], j3 = col[t + 3];
        int j4 = col[t + 4], j5 = col[t + 5], j6 = col[t + 6], j7 = col[t + 7];
        ushort4 u0 = *(const ushort4*)(hcat + (size_t)j0 * 256 + f0);
        ushort4 u1 = *(const ushort4*)(hcat + (size_t)j1 * 256 + f0);
        ushort4 u2 = *(const ushort4*)(hcat + (size_t)j2 * 256 + f0);
        ushort4 u3 = *(const ushort4*)(hcat + (size_t)j3 * 256 + f0);
        ushort4 u4 = *(const ushort4*)(hcat + (size_t)j4 * 256 + f0);
        ushort4 u5 = *(const ushort4*)(hcat + (size_t)j5 * 256 + f0);
        ushort4 u6 = *(const ushort4*)(hcat + (size_t)j6 * 256 + f0);
        ushort4 u7 = *(const ushort4*)(hcat + (size_t)j7 * 256 + f0);
        ACC4(u0) ACC4(u1) ACC4(u2) ACC4(u3) ACC4(u4) ACC4(u5) ACC4(u6) ACC4(u7)
        t += 8;
    }
    if (t + 3 < e) {
        int j0 = col[t], j1 = col[t + 1], j2 = col[t + 2], j3 = col[t + 3];
        ushort4 u0 = *(const ushort4*)(hcat + (size_t)j0 * 256 + f0);
        ushort4 u1 = *(const ushort4*)(hcat + (size_t)j1 * 256 + f0);
        ushort4 u2 = *(const ushort4*)(hcat + (size_t)j2 * 256 + f0);
        ushort4 u3 = *(const ushort4*)(hcat + (size_t)j3 * 256 + f0);
        ACC4(u0) ACC4(u1) ACC4(u2) ACC4(u3)
        t += 4;
    }
    if (t + 1 < e) {
        int j0 = col[t], j1 = col[t + 1];
        ushort4 u0 = *(const ushort4*)(hcat + (size_t)j0 * 256 + f0);
        ushort4 u1 = *(const ushort4*)(hcat + (size_t)j1 * 256 + f0);
        ACC4(u0) ACC4(u1)
        t += 2;
    }
    if (t < e) {
        ushort4 u0 = *(const ushort4*)(hcat + (size_t)col[t] * 256 + f0);
        ACC4(u0)
    }
    float di = 1.0f / fmaxf((float)(e - s), 1.0f);
    ushort4 o;
    o.x = f2bf(a0 * di); o.y = f2bf(a1 * di); o.z = f2bf(a2 * di); o.w = f2bf(a3 * di);
    *(ushort4*)(hcat + (size_t)i * 256 + 128 + f0) = o;
}

// ---------------- weight prep (transposed bf16) ----------------
__global__ __launch_bounds__(256) void wprep1_kernel(const float* __restrict__ Wr1, const float* __restrict__ Wl1,
                                                     const float* __restrict__ Wres, unsigned short* __restrict__ Bt) {
    int idx = blockIdx.x * 256 + threadIdx.x;   // n*128 + k
    if (idx >= 256 * 128) return;
    int n = idx >> 7;
    int k = idx & 127;
    float v;
    if (n < 128) v = (k < 64) ? Wr1[k * 128 + n] : Wl1[(k - 64) * 128 + n];
    else         v = (k < 64) ? Wres[k * 128 + (n - 128)] : 0.f;
    Bt[idx] = f2bf(v);
}

__global__ __launch_bounds__(256) void wprep23_kernel(const float* __restrict__ Wl, const float* __restrict__ Wr,
                                                      unsigned short* __restrict__ Bt) {
    int idx = blockIdx.x * 256 + threadIdx.x;   // n*256 + k
    if (idx >= 128 * 256) return;
    int n = idx >> 8;
    int k = idx & 255;
    float v = (k < 128) ? Wr[k * 128 + n] : Wl[(k - 128) * 128 + n];
    Bt[idx] = f2bf(v);
}

// ---------------- MFMA bf16 GEMM: C[M x ...] = A[M x lda] @ Bt^T, row-major bf16 ----------------
__global__ __launch_bounds__(256) void mgemm_kernel(const unsigned short* __restrict__ A, int lda,
                                                    const unsigned short* __restrict__ Bt, int M,
                                                    const float* __restrict__ bias,
                                                    unsigned short* __restrict__ C, int ldc) {
    __shared__ unsigned short As[128 * LP];
    __shared__ unsigned short Bs[128 * LP];
    int tid = threadIdx.x;
    int m0 = blockIdx.x * 128;
    int n0 = blockIdx.y * 128;

    int lane = tid & 63;
    int wave = tid >> 6;
    int wm = (wave & 1) * 64;
    int wn = (wave >> 1) * 64;
    int lm = lane & 15;
    int lk = (lane >> 4) * 8;

    float4v acc[4][4];
    #pragma unroll
    for (int i = 0; i < 4; i++)
        #pragma unroll
        for (int j = 0; j < 4; j++) acc[i][j] = (float4v)0.f;

    int sr = tid >> 3;          // staging row 0..31
    int sc = (tid & 7) * 8;     // staging col (shorts)

    for (int ks = 0; ks < lda; ks += 64) {
        if (ks) __syncthreads();
        int kk = ks + sc;
        #pragma unroll
        for (int rr = 0; rr < 128; rr += 32) {
            int r = sr + rr;
            int gm = m0 + r; if (gm > M - 1) gm = M - 1;
            ulonglong2 va = *(const ulonglong2*)(A + (size_t)gm * lda + kk);
            *(ulonglong2*)&As[r * LP + sc] = va;
            ulonglong2 vb = *(const ulonglong2*)(Bt + (size_t)(n0 + r) * lda + kk);
            *(ulonglong2*)&Bs[r * LP + sc] = vb;
        }
        __syncthreads();

        #pragma unroll
        for (int k0 = 0; k0 < 64; k0 += 32) {
            short8v af[4], bf[4];
            #pragma unroll
            for (int i = 0; i < 4; i++)
                af[i] = *(const short8v*)&As[(wm + i * 16 + lm) * LP + k0 + lk];
            #pragma unroll
            for (int j = 0; j < 4; j++)
                bf[j] = *(const short8v*)&Bs[(wn + j * 16 + lm) * LP + k0 + lk];
            #pragma unroll
            for (int i = 0; i < 4; i++)
                #pragma unroll
                for (int j = 0; j < 4; j++)
                    acc[i][j] = __builtin_amdgcn_mfma_f32_16x16x32_bf16(af[i], bf[j], acc[i][j], 0, 0, 0);
        }
    }

    int r0b = (lane >> 4) * 4;
    #pragma unroll
    for (int i = 0; i < 4; i++) {
        #pragma unroll
        for (int j = 0; j < 4; j++) {
            int cc = n0 + wn + j * 16 + (lane & 15);
            float bv = (bias != nullptr) ? bias[cc] : 0.f;
            #pragma unroll
            for (int r = 0; r < 4; r++) {
                int m = m0 + wm + i * 16 + r0b + r;
                if (m < M) {
                    float v = acc[i][j][r];
                    if (bias != nullptr) v = fmaxf(v + bv, 0.f);
                    C[(size_t)m * ldc + cc] = f2bf(v);
                }
            }
        }
    }
}

// ---------------- layer1 epilogue: t=Ub[:,0:128]+b1 -> LN -> relu -> + Ub[:,128:256]+bres ----------------
__global__ __launch_bounds__(256) void ln_kernel(const unsigned short* __restrict__ Ub, const float* __restrict__ b1,
                                                 const float* __restrict__ ln_g, const float* __restrict__ ln_b,
                                                 const float* __restrict__ bres, unsigned short* __restrict__ hcat) {
    int tid = threadIdx.x;
    int grp = tid >> 7;
    int f = tid & 127;
    int i = blockIdx.x * 2 + grp;
    bool valid = i < N_NODES;
    float t = 0.f;
    if (valid) t = bf2f(Ub[(size_t)i * 256 + f]) + b1[f];
    float s = t, s2 = t * t;
    #pragma unroll
    for (int off = 32; off; off >>= 1) {
        s += __shfl_down(s, off);
        s2 += __shfl_down(s2, off);
    }
    __shared__ float rs[4], rs2[4];
    int wave = tid >> 6;
    if ((tid & 63) == 0) { rs[wave] = s; rs2[wave] = s2; }
    __syncthreads();
    float sum = rs[grp * 2] + rs[grp * 2 + 1];
    float sumsq = rs2[grp * 2] + rs2[grp * 2 + 1];
    float mu = sum * (1.f / 128.f);
    float var = sumsq * (1.f / 128.f) - mu * mu;
    float r = rsqrtf(var + 1e-5f);
    if (valid) {
        float y = (t - mu) * r * ln_g[f] + ln_b[f];
        y = fmaxf(y, 0.f);
        y += bf2f(Ub[(size_t)i * 256 + 128 + f]) + bres[f];
        hcat[(size_t)i * 256 + f] = f2bf(y);
    }
}

// ---------------- layer4 (sorted space) ----------------
__global__ __launch_bounds__(256) void pq_kernel(const unsigned short* __restrict__ hcat, const float* __restrict__ Wl4,
                                                 const float* __restrict__ Wr4, const float* __restrict__ b4,
                                                 float* __restrict__ p, float* __restrict__ q) {
    int tid = threadIdx.x;
    int lane = tid & 63;
    int w = tid >> 6;
    int i = blockIdx.x * 4 + w;
    if (i >= N_NODES) return;
    const unsigned short* hr = hcat + (size_t)i * 256;
    float a = bf2f(hr[lane]), b = bf2f(hr[64 + lane]);
    float pp = a * Wl4[lane] + b * Wl4[64 + lane];
    float qq = a * Wr4[lane] + b * Wr4[64 + lane];
    #pragma unroll
    for (int off = 32; off; off >>= 1) {
        pp += __shfl_down(pp, off);
        qq += __shfl_down(qq, off);
    }
    if (lane == 0) { p[i] = pp; q[i] = qq + b4[0]; }
}

__global__ __launch_bounds__(256) void final_kernel(const float* __restrict__ p, const float* __restrict__ q,
                                                    const int* __restrict__ row_ptr, const int* __restrict__ col,
                                                    const int* __restrict__ ord, float* __restrict__ out) {
    int i = blockIdx.x * 256 + threadIdx.x;   // sorted slot
    if (i >= N_NODES) return;
    int s = row_ptr[i], e = row_ptr[i + 1];
    float acc = 0.f;
    int t = s;
    for (; t + 3 < e; t += 4)
        acc += p[col[t]] + p[col[t + 1]] + p[col[t + 2]] + p[col[t + 3]];
    for (; t < e; t++) acc += p[col[t]];
    float di = 1.0f / fmaxf((float)(e - s), 1.0f);
    out[ord[i]] = acc * di + q[i];
}

// ---------------- launch ----------------

extern "C" void kernel_launch(void* const* d_in, const int* in_sizes, int n_in,
                              void* d_out, int out_size, void* d_ws, size_t ws_size,
                              hipStream_t stream) {
    const float* x    = (const float*)d_in[0];
    const int*   ei   = (const int*)d_in[1];
    const float* Wl1  = (const float*)d_in[2];
    const float* Wr1  = (const float*)d_in[3];
    const float* b1   = (const float*)d_in[4];
    const float* ln_g = (const float*)d_in[5];
    const float* ln_b = (const float*)d_in[6];
    const float* Wres = (const float*)d_in[7];
    const float* bres = (const float*)d_in[8];
    const float* Wl2  = (const float*)d_in[9];
    const float* Wr2  = (const float*)d_in[10];
    const float* b2   = (const float*)d_in[11];
    const float* Wl3  = (const float*)d_in[12];
    const float* Wr3  = (const float*)d_in[13];
    const float* b3   = (const float*)d_in[14];
    const float* Wl4  = (const float*)d_in[15];
    const float* Wr4  = (const float*)d_in[16];
    const float* b4   = (const float*)d_in[17];
    float* out = (float*)d_out;

    char* w = (char*)d_ws;
    size_t off = 0;
    auto alloc = [&](size_t bytes) -> void* {
        off = (off + 255) & ~(size_t)255;
        void* pp = w + off;
        off += bytes;
        return pp;
    };

    int*   deg        = (int*)alloc(N_NODES * 4);       // original space
    int*   deg_s      = (int*)alloc(N_NODES * 4);       // sorted space
    int*   row_ptr    = (int*)alloc((N_NODES + 1) * 4); // sorted space
    int*   bsum       = (int*)alloc(512);               // 128 ints, reused by both scans
    int*   col        = (int*)alloc(N_EDGES * 4);       // sorted-space src ids
    int*   bucket_off = (int*)alloc((NBKT + 1) * 4);
    int*   bh2        = (int*)alloc(BH2_N * 4);         // per-(bucket, block) counts/bases
    int*   bh         = (int*)alloc(64 * SORT_BLOCKS * 4);
    int*   ord        = (int*)alloc(N_NODES * 4);       // slot -> orig
    int*   rank       = (int*)alloc(N_NODES * 4);       // orig -> slot
    unsigned short* Btw  = (unsigned short*)alloc(128 * 256 * 2);
    unsigned short* xcat = (unsigned short*)alloc((size_t)N_NODES * 128 * 2);  // [x | aggx] bf16
    unsigned short* hcat = (unsigned short*)alloc((size_t)N_NODES * 256 * 2);  // [h | aggh] bf16
    float* U       = (float*)alloc((size_t)N_NODES * 256 * 4);   // scratch: packed pairs, then Ub
    float* p       = (float*)alloc(N_NODES * 4);
    float* q       = (float*)alloc(N_NODES * 4);
    int* packed = (int*)U;                   // CSR build scratch (done before U reused)
    unsigned short* Ub = (unsigned short*)U; // layer-1 GEMM out, N x 256 bf16 row-major
    (void)ws_size; (void)n_in; (void)in_sizes; (void)out_size;

    const int NB = (N_NODES + 255) / 256;
    const int SCB = (N_NODES + 1023) / 1024;            // 98
    const int BHB = (BH2_N + 1023) / 1024;              // 92
    const int MB = (N_NODES + 127) / 128;               // 782

    // --- CSR build: hist -> scan -> scatter(packed) -> deg; degree sort; row_ptr; fill ---
    bkt_hist_kernel<<<SCAT_BLOCKS, 256, 0, stream>>>(ei, bh2);
    gscan_a_kernel<<<BHB, 256, 0, stream>>>(bh2, bsum, BH2_N);
    scan_b_kernel<<<1, 64, 0, stream>>>(bsum, BHB);
    gscan_c_kernel<<<BHB, 256, 0, stream>>>(bh2, bsum, BH2_N);
    extract_off_kernel<<<(NBKT + 256) / 256, 256, 0, stream>>>(bh2, bucket_off);
    bkt_scatter2_kernel<<<SCAT_BLOCKS, 256, 0, stream>>>(ei, bh2, packed);
    bkt_deg2_kernel<<<NBKT, 256, 0, stream>>>(packed, bucket_off, deg);
    dsort_hist_kernel<<<SORT_BLOCKS, 256, 0, stream>>>(deg, bh);
    dsort_scan_kernel<<<1, 256, 0, stream>>>(bh);
    dsort_scat_kernel<<<SORT_BLOCKS, 256, 0, stream>>>(deg, bh, ord, rank, deg_s);
    gscan_a_kernel<<<SCB, 256, 0, stream>>>(deg_s, bsum, N_NODES);
    scan_b_kernel<<<1, 128, 0, stream>>>(bsum, SCB);
    scan_c_row_kernel<<<SCB, 256, 0, stream>>>(deg_s, bsum, row_ptr);
    bkt_fill2_kernel<<<NBKT, 256, 0, stream>>>(packed, bucket_off, row_ptr, rank, col);

    // --- layer 1: xcat = [x | mean-agg(x)] bf16 (sorted space); GEMM -> Ub; LN -> hcat[:,0:128] ---
    xbf_kernel<<<(N_NODES * 16 + 255) / 256, 256, 0, stream>>>(x, rank, xcat);
    agg64_kernel<<<(N_NODES + 15) / 16, 256, 0, stream>>>(xcat, row_ptr, col);
    wprep1_kernel<<<128, 256, 0, stream>>>(Wr1, Wl1, Wres, Btw);
    mgemm_kernel<<<dim3(MB, 2), 256, 0, stream>>>(xcat, 128, Btw, N_NODES, nullptr, Ub, 256);
    ln_kernel<<<(N_NODES + 1) / 2, 256, 0, stream>>>(Ub, b1, ln_g, ln_b, bres, hcat);

    // --- layer 2: agg(h) -> hcat[:,128:256]; GEMM [h|aggh] -> hcat[:,0:128] (bias+relu) ---
    agg128_kernel<<<(N_NODES + 7) / 8, 256, 0, stream>>>(hcat, row_ptr, col);
    wprep23_kernel<<<128, 256, 0, stream>>>(Wl2, Wr2, Btw);
    mgemm_kernel<<<dim3(MB, 1), 256, 0, stream>>>(hcat, 256, Btw, N_NODES, b2, hcat, 256);

    // --- layer 3 ---
    agg128_kernel<<<(N_NODES + 7) / 8, 256, 0, stream>>>(hcat, row_ptr, col);
    wprep23_kernel<<<128, 256, 0, stream>>>(Wl3, Wr3, Btw);
    mgemm_kernel<<<dim3(MB, 1), 256, 0, stream>>>(hcat, 256, Btw, N_NODES, b3, hcat, 256);

    // --- layer 4 ---
    pq_kernel<<<(N_NODES + 3) / 4, 256, 0, stream>>>(hcat, Wl4, Wr4, b4, p, q);
    final_kernel<<<NB, 256, 0, stream>>>(p, q, row_ptr, col, ord, out);
}

// Round 10
// 474.582 us; speedup vs baseline: 2.8347x; 1.1099x over previous
//
#include <hip/hip_runtime.h>
#include <hip/hip_bf16.h>

#define N_NODES 100000
#define N_EDGES 1600000

#define NBKT 782                 // ceil(N_NODES / 128)
#define BKT_CHUNK 13334          // ceil(N_EDGES / 120)
#define SCAT_BLOCKS 120
#define LP 72                    // padded LDS row length in shorts (64 + 8)

#define SORT_BLOCKS 40
#define SORT_CHUNK 2500          // 40 * 2500 = 100000
#define BH2_N (NBKT * SCAT_BLOCKS)   // 93840

typedef __attribute__((ext_vector_type(8))) short short8v;
typedef __attribute__((ext_vector_type(4))) float float4v;

__device__ __forceinline__ unsigned short f2bf(float f) {
    unsigned int u = __float_as_uint(f);
    u = (u + 0x7FFFu + ((u >> 16) & 1u)) >> 16;   // RTNE
    return (unsigned short)u;
}
__device__ __forceinline__ float bf2f(unsigned short b) {
    return __uint_as_float((unsigned int)b << 16);
}

// ---------------- CSR build: one histogram pass + big scan + one-pass scatter ----------------

__global__ __launch_bounds__(256) void bkt_hist_kernel(const int* __restrict__ ei, int* __restrict__ bh2) {
    __shared__ int h[NBKT];
    int tid = threadIdx.x;
    for (int i = tid; i < NBKT; i += 256) h[i] = 0;
    __syncthreads();
    int start = blockIdx.x * BKT_CHUNK;
    int end = start + BKT_CHUNK; if (end > N_EDGES) end = N_EDGES;
    for (int i = start + tid; i < end; i += 256) {
        int d = ei[N_EDGES + i];
        atomicAdd(&h[d >> 7], 1);
    }
    __syncthreads();
    for (int i = tid; i < NBKT; i += 256) bh2[i * SCAT_BLOCKS + blockIdx.x] = h[i];
}

__global__ __launch_bounds__(256) void gscan_a_kernel(const int* __restrict__ in, int* __restrict__ bsum, int n) {
    __shared__ int lds[256];
    int tid = threadIdx.x;
    int base = blockIdx.x * 1024 + tid * 4;
    int s = 0;
    #pragma unroll
    for (int i = 0; i < 4; i++) s += (base + i < n) ? in[base + i] : 0;
    lds[tid] = s;
    __syncthreads();
    for (int off = 128; off; off >>= 1) {
        if (tid < off) lds[tid] += lds[tid + off];
        __syncthreads();
    }
    if (tid == 0) bsum[blockIdx.x] = lds[0];
}

__global__ void scan_b_kernel(int* __restrict__ bsum, int nb) {
    if (threadIdx.x == 0 && blockIdx.x == 0) {
        int acc = 0;
        for (int i = 0; i < nb; i++) { int v = bsum[i]; bsum[i] = acc; acc += v; }
    }
}

__global__ __launch_bounds__(256) void gscan_c_kernel(int* __restrict__ data, const int* __restrict__ bsum, int n) {
    __shared__ int lds[256];
    int tid = threadIdx.x;
    int base = blockIdx.x * 1024 + tid * 4;
    int v[4];
    int s = 0;
    #pragma unroll
    for (int i = 0; i < 4; i++) {
        v[i] = (base + i < n) ? data[base + i] : 0;
        s += v[i];
    }
    lds[tid] = s;
    __syncthreads();
    for (int off = 1; off < 256; off <<= 1) {
        int y = 0;
        if (tid >= off) y = lds[tid - off];
        __syncthreads();
        if (tid >= off) lds[tid] += y;
        __syncthreads();
    }
    int run = bsum[blockIdx.x] + lds[tid] - s;
    #pragma unroll
    for (int i = 0; i < 4; i++) {
        if (base + i < n) data[base + i] = run;
        run += v[i];
    }
}

__global__ __launch_bounds__(256) void extract_off_kernel(const int* __restrict__ bh2, int* __restrict__ bucket_off) {
    int i = blockIdx.x * 256 + threadIdx.x;
    if (i < NBKT) bucket_off[i] = bh2[i * SCAT_BLOCKS];
    if (i == NBKT) bucket_off[NBKT] = N_EDGES;
}

__global__ __launch_bounds__(256) void bkt_scatter2_kernel(const int* __restrict__ ei, const int* __restrict__ bh2,
                                                           int* __restrict__ packed) {
    __shared__ int h[NBKT];
    __shared__ int base[NBKT];
    int tid = threadIdx.x;
    for (int i = tid; i < NBKT; i += 256) { h[i] = 0; base[i] = bh2[i * SCAT_BLOCKS + blockIdx.x]; }
    __syncthreads();
    int start = blockIdx.x * BKT_CHUNK;
    int end = start + BKT_CHUNK; if (end > N_EDGES) end = N_EDGES;
    for (int i = start + tid; i < end; i += 256) {
        int s = ei[i];
        int d = ei[N_EDGES + i];
        int b = d >> 7;
        int pos = base[b] + atomicAdd(&h[b], 1);
        packed[pos] = (s << 7) | (d & 127);
    }
}

__global__ __launch_bounds__(256) void bkt_deg2_kernel(const int* __restrict__ packed, const int* __restrict__ bucket_off,
                                                       int* __restrict__ deg) {
    __shared__ int c[128];
    int tid = threadIdx.x;
    if (tid < 128) c[tid] = 0;
    __syncthreads();
    int s0 = bucket_off[blockIdx.x], s1 = bucket_off[blockIdx.x + 1];
    for (int i = s0 + tid; i < s1; i += 256) atomicAdd(&c[packed[i] & 127], 1);
    __syncthreads();
    int node = blockIdx.x * 128 + tid;
    if (tid < 128 && node < N_NODES) deg[node] = c[tid];
}

__global__ __launch_bounds__(256) void bkt_fill2_kernel(const int* __restrict__ packed, const int* __restrict__ bucket_off,
                                                        const int* __restrict__ row_ptr, const int* __restrict__ rank,
                                                        int* __restrict__ col) {
    __shared__ int rp[128];
    __shared__ int c[128];
    int tid = threadIdx.x;
    int node = blockIdx.x * 128 + tid;
    if (tid < 128) {
        rp[tid] = (node < N_NODES) ? row_ptr[rank[node]] : 0;
        c[tid] = 0;
    }
    __syncthreads();
    int s0 = bucket_off[blockIdx.x], s1 = bucket_off[blockIdx.x + 1];
    for (int i = s0 + tid; i < s1; i += 256) {
        int p = packed[i];
        int dl = p & 127;
        int pos = rp[dl] + atomicAdd(&c[dl], 1);
        col[pos] = rank[p >> 7];
    }
}

// ---------------- degree counting sort (contention-free) ----------------
__global__ __launch_bounds__(256) void dsort_hist_kernel(const int* __restrict__ deg, int* __restrict__ bh) {
    __shared__ int h[64];
    int tid = threadIdx.x;
    if (tid < 64) h[tid] = 0;
    __syncthreads();
    int start = blockIdx.x * SORT_CHUNK;
    int end = start + SORT_CHUNK; if (end > N_NODES) end = N_NODES;
    for (int i = start + tid; i < end; i += 256) atomicAdd(&h[min(deg[i], 63)], 1);
    __syncthreads();
    if (tid < 64) bh[tid * SORT_BLOCKS + blockIdx.x] = h[tid];
}

__global__ __launch_bounds__(256) void dsort_scan_kernel(int* __restrict__ bh) {
    __shared__ int ps[256];
    int tid = threadIdx.x;
    int v[10];
    int s = 0;
    #pragma unroll
    for (int k = 0; k < 10; k++) { v[k] = bh[tid * 10 + k]; s += v[k]; }
    ps[tid] = s;
    __syncthreads();
    for (int off = 1; off < 256; off <<= 1) {
        int y = 0;
        if (tid >= off) y = ps[tid - off];
        __syncthreads();
        if (tid >= off) ps[tid] += y;
        __syncthreads();
    }
    int run = ps[tid] - s;
    #pragma unroll
    for (int k = 0; k < 10; k++) { int t = v[k]; bh[tid * 10 + k] = run; run += t; }
}

__global__ __launch_bounds__(256) void dsort_scat_kernel(const int* __restrict__ deg, const int* __restrict__ bh,
                                                         int* __restrict__ ord, int* __restrict__ rank,
                                                         int* __restrict__ deg_s) {
    __shared__ int h[64];
    __shared__ int base[64];
    int tid = threadIdx.x;
    if (tid < 64) { h[tid] = 0; base[tid] = bh[tid * SORT_BLOCKS + blockIdx.x]; }
    __syncthreads();
    int start = blockIdx.x * SORT_CHUNK;
    int end = start + SORT_CHUNK; if (end > N_NODES) end = N_NODES;
    for (int i = start + tid; i < end; i += 256) {
        int d = deg[i];
        int b = min(d, 63);
        int pos = base[b] + atomicAdd(&h[b], 1);
        ord[pos] = i;
        rank[i] = pos;
        deg_s[pos] = d;
    }
}

// ---------------- scan of deg_s -> row_ptr (sorted space, with sentinel) ----------------
__global__ __launch_bounds__(256) void scan_c_row_kernel(const int* __restrict__ deg, const int* __restrict__ bsum,
                                                         int* __restrict__ row_ptr) {
    __shared__ int lds[256];
    int tid = threadIdx.x;
    int base = blockIdx.x * 1024 + tid * 4;
    int v[4];
    int s = 0;
    #pragma unroll
    for (int i = 0; i < 4; i++) {
        int idx = base + i;
        v[i] = (idx < N_NODES) ? deg[idx] : 0;
        s += v[i];
    }
    lds[tid] = s;
    __syncthreads();
    for (int off = 1; off < 256; off <<= 1) {
        int y = 0;
        if (tid >= off) y = lds[tid - off];
        __syncthreads();
        if (tid >= off) lds[tid] += y;
        __syncthreads();
    }
    int run = bsum[blockIdx.x] + lds[tid] - s;
    #pragma unroll
    for (int i = 0; i < 4; i++) {
        int idx = base + i;
        if (idx < N_NODES) row_ptr[idx] = run;
        run += v[i];
    }
    if (blockIdx.x == 0 && tid == 0) row_ptr[N_NODES] = N_EDGES;
}

// ---------------- x (fp32, orig space) -> xcat[:,0:64] bf16 at rank[node], ld 128 ----------------
__global__ __launch_bounds__(256) void xbf_kernel(const float* __restrict__ x, const int* __restrict__ rank,
                                                  unsigned short* __restrict__ xcat) {
    int idx = blockIdx.x * 256 + threadIdx.x;   // one float4 per thread
    if (idx < N_NODES * 16) {
        int node = idx >> 4;
        int f0 = (idx & 15) * 4;
        int rn = rank[node];
        float4 v = *(const float4*)(x + (size_t)idx * 4);
        ushort4 o;
        o.x = f2bf(v.x); o.y = f2bf(v.y); o.z = f2bf(v.z); o.w = f2bf(v.w);
        *(ushort4*)(xcat + (size_t)rn * 128 + f0) = o;
    }
}

#define ACC4(u) { a0 += bf2f(u.x); a1 += bf2f(u.y); a2 += bf2f(u.z); a3 += bf2f(u.w); }

// ---------------- layer-1 agg: mean of xcat[j,0:64] -> xcat[i,64:128]; 16 lanes/node ----------------
__global__ __launch_bounds__(256) void agg64_kernel(unsigned short* __restrict__ xcat,
                                                    const int* __restrict__ row_ptr, const int* __restrict__ col) {
    int tid = threadIdx.x;
    int i = blockIdx.x * 16 + (tid >> 4);
    if (i >= N_NODES) return;
    int f0 = (tid & 15) * 4;
    int s = row_ptr[i], e = row_ptr[i + 1];
    float a0 = 0.f, a1 = 0.f, a2 = 0.f, a3 = 0.f;
    int t = s;
    while (t + 7 < e) {
        int j0 = col[t], j1 = col[t + 1], j2 = col[t + 2], j3 = col[t + 3];
        int j4 = col[t + 4], j5 = col[t + 5], j6 = col[t + 6], j7 = col[t + 7];
        ushort4 u0 = *(const ushort4*)(xcat + (size_t)j0 * 128 + f0);
        ushort4 u1 = *(const ushort4*)(xcat + (size_t)j1 * 128 + f0);
        ushort4 u2 = *(const ushort4*)(xcat + (size_t)j2 * 128 + f0);
        ushort4 u3 = *(const ushort4*)(xcat + (size_t)j3 * 128 + f0);
        ushort4 u4 = *(const ushort4*)(xcat + (size_t)j4 * 128 + f0);
        ushort4 u5 = *(const ushort4*)(xcat + (size_t)j5 * 128 + f0);
        ushort4 u6 = *(const ushort4*)(xcat + (size_t)j6 * 128 + f0);
        ushort4 u7 = *(const ushort4*)(xcat + (size_t)j7 * 128 + f0);
        ACC4(u0) ACC4(u1) ACC4(u2) ACC4(u3) ACC4(u4) ACC4(u5) ACC4(u6) ACC4(u7)
        t += 8;
    }
    if (t + 3 < e) {
        int j0 = col[t], j1 = col[t + 1], j2 = col[t + 2], j3 = col[t + 3];
        ushort4 u0 = *(const ushort4*)(xcat + (size_t)j0 * 128 + f0);
        ushort4 u1 = *(const ushort4*)(xcat + (size_t)j1 * 128 + f0);
        ushort4 u2 = *(const ushort4*)(xcat + (size_t)j2 * 128 + f0);
        ushort4 u3 = *(const ushort4*)(xcat + (size_t)j3 * 128 + f0);
        ACC4(u0) ACC4(u1) ACC4(u2) ACC4(u3)
        t += 4;
    }
    if (t + 1 < e) {
        int j0 = col[t], j1 = col[t + 1];
        ushort4 u0 = *(const ushort4*)(xcat + (size_t)j0 * 128 + f0);
        ushort4 u1 = *(const ushort4*)(xcat + (size_t)j1 * 128 + f0);
        ACC4(u0) ACC4(u1)
        t += 2;
    }
    if (t < e) {
        ushort4 u0 = *(const ushort4*)(xcat + (size_t)col[t] * 128 + f0);
        ACC4(u0)
    }
    float di = 1.0f / fmaxf((float)(e - s), 1.0f);
    ushort4 o;
    o.x = f2bf(a0 * di); o.y = f2bf(a1 * di); o.z = f2bf(a2 * di); o.w = f2bf(a3 * di);
    *(ushort4*)(xcat + (size_t)i * 128 + 64 + f0) = o;
}

// ---------------- layers 2/3 agg: mean of hcat[j,0:128] -> hcat[i,128:256]; 32 lanes/node ----------------
__global__ __launch_bounds__(256) void agg128_kernel(unsigned short* __restrict__ hcat,
                                                     const int* __restrict__ row_ptr, const int* __restrict__ col) {
    int tid = threadIdx.x;
    int i = blockIdx.x * 8 + (tid >> 5);
    if (i >= N_NODES) return;
    int f0 = (tid & 31) * 4;
    int s = row_ptr[i], e = row_ptr[i + 1];
    float a0 = 0.f, a1 = 0.f, a2 = 0.f, a3 = 0.f;
    int t = s;
    while (t + 7 < e) {
        int j0 = col[t], j1 = col[t + 1], j2 = col[t + 2], j3 = col[t + 3];
        int j4 = col[t + 4], j5 = col[t + 5], j6 = col[t + 6], j7 = col[t + 7];
        ushort4 u0 = *(const ushort4*)(hcat + (size_t)j0 * 256 + f0);
        ushort4 u1 = *(const ushort4*)(hcat + (size_t)j1 * 256 + f0);
        ushort4 u2 = *(const ushort4*)(hcat + (size_t)j2 * 256 + f0);
        ushort4 u3 = *(const ushort4*)(hcat + (size_t)j3 * 256 + f0);
        ushort4 u4 = *(const ushort4*)(hcat + (size_t)j4 * 256 + f0);
        ushort4 u5 = *(const ushort4*)(hcat + (size_t)j5 * 256 + f0);
        ushort4 u6 = *(const ushort4*)(hcat + (size_t)j6 * 256 + f0);
        ushort4 u7 = *(const ushort4*)(hcat + (size_t)j7 * 256 + f0);
        ACC4(u0) ACC4(u1) ACC4(u2) ACC4(u3) ACC4(u4) ACC4(u5) ACC4(u6) ACC4(u7)
        t += 8;
    }
    if (t + 3 < e) {
        int j0 = col[t], j1 = col[t + 1], j2 = col[t + 2], j3 = col[t + 3];
        ushort4 u0 = *(const ushort4*)(hcat + (size_t)j0 * 256 + f0);
        ushort4 u1 = *(const ushort4*)(hcat + (size_t)j1 * 256 + f0);
        ushort4 u2 = *(const ushort4*)(hcat + (size_t)j2 * 256 + f0);
        ushort4 u3 = *(const ushort4*)(hcat + (size_t)j3 * 256 + f0);
        ACC4(u0) ACC4(u1) ACC4(u2) ACC4(u3)
        t += 4;
    }
    if (t + 1 < e) {
        int j0 = col[t], j1 = col[t + 1];
        ushort4 u0 = *(const ushort4*)(hcat + (size_t)j0 * 256 + f0);
        ushort4 u1 = *(const ushort4*)(hcat + (size_t)j1 * 256 + f0);
        ACC4(u0) ACC4(u1)
        t += 2;
    }
    if (t < e) {
        ushort4 u0 = *(const ushort4*)(hcat + (size_t)col[t] * 256 + f0);
        ACC4(u0)
    }
    float di = 1.0f / fmaxf((float)(e - s), 1.0f);
    ushort4 o;
    o.x = f2bf(a0 * di); o.y = f2bf(a1 * di); o.z = f2bf(a2 * di); o.w = f2bf(a3 * di);
    *(ushort4*)(hcat + (size_t)i * 256 + 128 + f0) = o;
}

// ---------------- weight prep (transposed bf16) ----------------
__global__ __launch_bounds__(256) void wprep1_kernel(const float* __restrict__ Wr1, const float* __restrict__ Wl1,
                                                     const float* __restrict__ Wres, unsigned short* __restrict__ Bt) {
    int idx = blockIdx.x * 256 + threadIdx.x;   // n*128 + k
    if (idx >= 256 * 128) return;
    int n = idx >> 7;
    int k = idx & 127;
    float v;
    if (n < 128) v = (k < 64) ? Wr1[k * 128 + n] : Wl1[(k - 64) * 128 + n];
    else         v = (k < 64) ? Wres[k * 128 + (n - 128)] : 0.f;
    Bt[idx] = f2bf(v);
}

__global__ __launch_bounds__(256) void wprep23_kernel(const float* __restrict__ Wl, const float* __restrict__ Wr,
                                                      unsigned short* __restrict__ Bt) {
    int idx = blockIdx.x * 256 + threadIdx.x;   // n*256 + k
    if (idx >= 128 * 256) return;
    int n = idx >> 8;
    int k = idx & 255;
    float v = (k < 128) ? Wr[k * 128 + n] : Wl[(k - 128) * 128 + n];
    Bt[idx] = f2bf(v);
}

// ---------------- layer-1 fused GEMM+LN: hcat[:,0:128] = relu(LN(xcat@Bt[0:128]^T + b1)) + xcat@Bt[128:256]^T + bres
// grid (MB). Block computes full 256-col rows: accT (cols 0..127), accR (cols 128..255).
__global__ __launch_bounds__(256) void mgemm1_ln_kernel(const unsigned short* __restrict__ A,
                                                        const unsigned short* __restrict__ Bt, int M,
                                                        const float* __restrict__ b1, const float* __restrict__ ln_g,
                                                        const float* __restrict__ ln_b, const float* __restrict__ bres,
                                                        unsigned short* __restrict__ hcat) {
    __shared__ unsigned short As[128 * LP];
    __shared__ unsigned short Bs[256 * LP];
    __shared__ float lsum[2][128], lsq[2][128];
    int tid = threadIdx.x;
    int m0 = blockIdx.x * 128;

    int lane = tid & 63;
    int wave = tid >> 6;
    int wm = (wave & 1) * 64;
    int wn = (wave >> 1) * 64;
    int lm = lane & 15;
    int lk = (lane >> 4) * 8;

    float4v accT[4][4], accR[4][4];
    #pragma unroll
    for (int i = 0; i < 4; i++)
        #pragma unroll
        for (int j = 0; j < 4; j++) { accT[i][j] = (float4v)0.f; accR[i][j] = (float4v)0.f; }

    int sr = tid >> 3;          // staging row 0..31
    int sc = (tid & 7) * 8;     // staging col (shorts)

    for (int ks = 0; ks < 128; ks += 64) {
        if (ks) __syncthreads();
        int kk = ks + sc;
        #pragma unroll
        for (int rr = 0; rr < 384; rr += 32) {
            int r = sr + rr;
            if (r < 128) {
                int gm = m0 + r; if (gm > M - 1) gm = M - 1;
                *(ulonglong2*)&As[r * LP + sc] = *(const ulonglong2*)(A + (size_t)gm * 128 + kk);
            } else {
                int br = r - 128;
                *(ulonglong2*)&Bs[br * LP + sc] = *(const ulonglong2*)(Bt + (size_t)br * 128 + kk);
            }
        }
        __syncthreads();

        #pragma unroll
        for (int k0 = 0; k0 < 64; k0 += 32) {
            short8v af[4], bfT[4], bfR[4];
            #pragma unroll
            for (int i = 0; i < 4; i++)
                af[i] = *(const short8v*)&As[(wm + i * 16 + lm) * LP + k0 + lk];
            #pragma unroll
            for (int j = 0; j < 4; j++) {
                bfT[j] = *(const short8v*)&Bs[(wn + j * 16 + lm) * LP + k0 + lk];
                bfR[j] = *(const short8v*)&Bs[(128 + wn + j * 16 + lm) * LP + k0 + lk];
            }
            #pragma unroll
            for (int i = 0; i < 4; i++)
                #pragma unroll
                for (int j = 0; j < 4; j++) {
                    accT[i][j] = __builtin_amdgcn_mfma_f32_16x16x32_bf16(af[i], bfT[j], accT[i][j], 0, 0, 0);
                    accR[i][j] = __builtin_amdgcn_mfma_f32_16x16x32_bf16(af[i], bfR[j], accR[i][j], 0, 0, 0);
                }
        }
    }

    // epilogue: LN over the 128 t-cols per row, then + residual
    int q = lane >> 4;
    int wnidx = wave >> 1;
    float b1v[4], gv[4], bbv[4], brv[4];
    #pragma unroll
    for (int j = 0; j < 4; j++) {
        int cc = wn + j * 16 + lm;
        b1v[j] = b1[cc]; gv[j] = ln_g[cc]; bbv[j] = ln_b[cc]; brv[j] = bres[cc];
    }
    // per (i, r): partial sums over this lane's 4 cols, quad-reduce, stash in LDS
    #pragma unroll
    for (int i = 0; i < 4; i++) {
        #pragma unroll
        for (int r = 0; r < 4; r++) {
            float sp = 0.f, sq = 0.f;
            #pragma unroll
            for (int j = 0; j < 4; j++) {
                float tv = accT[i][j][r] + b1v[j];
                sp += tv; sq += tv * tv;
            }
            #pragma unroll
            for (int off = 1; off < 16; off <<= 1) {
                sp += __shfl_xor(sp, off);
                sq += __shfl_xor(sq, off);
            }
            if (lm == 0) {
                int m = wm + i * 16 + q * 4 + r;
                lsum[wnidx][m] = sp;
                lsq[wnidx][m] = sq;
            }
        }
    }
    __syncthreads();
    #pragma unroll
    for (int i = 0; i < 4; i++) {
        #pragma unroll
        for (int r = 0; r < 4; r++) {
            int m = wm + i * 16 + q * 4 + r;
            float sum = lsum[0][m] + lsum[1][m];
            float s2 = lsq[0][m] + lsq[1][m];
            float mu = sum * (1.f / 128.f);
            float var = s2 * (1.f / 128.f) - mu * mu;
            float rstd = rsqrtf(var + 1e-5f);
            int gm = m0 + m;
            if (gm < M) {
                #pragma unroll
                for (int j = 0; j < 4; j++) {
                    float tv = accT[i][j][r] + b1v[j];
                    float y = fmaxf((tv - mu) * rstd * gv[j] + bbv[j], 0.f) + accR[i][j][r] + brv[j];
                    hcat[(size_t)gm * 256 + wn + j * 16 + lm] = f2bf(y);
                }
            }
        }
    }
}

// ---------------- MFMA bf16 GEMM (layer 2): hcat[:,0:128] = relu(hcat@Bt^T + bias) ----------------
__global__ __launch_bounds__(256) void mgemm_kernel(const unsigned short* __restrict__ A, int lda,
                                                    const unsigned short* __restrict__ Bt, int M,
                                                    const float* __restrict__ bias,
                                                    unsigned short* __restrict__ C, int ldc) {
    __shared__ unsigned short As[128 * LP];
    __shared__ unsigned short Bs[128 * LP];
    int tid = threadIdx.x;
    int m0 = blockIdx.x * 128;
    int n0 = blockIdx.y * 128;

    int lane = tid & 63;
    int wave = tid >> 6;
    int wm = (wave & 1) * 64;
    int wn = (wave >> 1) * 64;
    int lm = lane & 15;
    int lk = (lane >> 4) * 8;

    float4v acc[4][4];
    #pragma unroll
    for (int i = 0; i < 4; i++)
        #pragma unroll
        for (int j = 0; j < 4; j++) acc[i][j] = (float4v)0.f;

    int sr = tid >> 3;
    int sc = (tid & 7) * 8;

    for (int ks = 0; ks < lda; ks += 64) {
        if (ks) __syncthreads();
        int kk = ks + sc;
        #pragma unroll
        for (int rr = 0; rr < 128; rr += 32) {
            int r = sr + rr;
            int gm = m0 + r; if (gm > M - 1) gm = M - 1;
            *(ulonglong2*)&As[r * LP + sc] = *(const ulonglong2*)(A + (size_t)gm * lda + kk);
            *(ulonglong2*)&Bs[r * LP + sc] = *(const ulonglong2*)(Bt + (size_t)(n0 + r) * lda + kk);
        }
        __syncthreads();

        #pragma unroll
        for (int k0 = 0; k0 < 64; k0 += 32) {
            short8v af[4], bf[4];
            #pragma unroll
            for (int i = 0; i < 4; i++)
                af[i] = *(const short8v*)&As[(wm + i * 16 + lm) * LP + k0 + lk];
            #pragma unroll
            for (int j = 0; j < 4; j++)
                bf[j] = *(const short8v*)&Bs[(wn + j * 16 + lm) * LP + k0 + lk];
            #pragma unroll
            for (int i = 0; i < 4; i++)
                #pragma unroll
                for (int j = 0; j < 4; j++)
                    acc[i][j] = __builtin_amdgcn_mfma_f32_16x16x32_bf16(af[i], bf[j], acc[i][j], 0, 0, 0);
        }
    }

    int r0b = (lane >> 4) * 4;
    #pragma unroll
    for (int i = 0; i < 4; i++) {
        #pragma unroll
        for (int j = 0; j < 4; j++) {
            int cc = n0 + wn + j * 16 + lm;
            float bv = (bias != nullptr) ? bias[cc] : 0.f;
            #pragma unroll
            for (int r = 0; r < 4; r++) {
                int m = m0 + wm + i * 16 + r0b + r;
                if (m < M) {
                    float v = acc[i][j][r];
                    if (bias != nullptr) v = fmaxf(v + bv, 0.f);
                    C[(size_t)m * ldc + cc] = f2bf(v);
                }
            }
        }
    }
}

// ---------------- layer-3 fused GEMM+pq: h3 never materialized ----------------
// p[m] = sum_cc relu(acc+b3)[cc] * Wl4[cc];  q[m] = sum_cc relu(acc+b3)[cc] * Wr4[cc] + b4
__global__ __launch_bounds__(256) void mgemm_pq_kernel(const unsigned short* __restrict__ A, int lda,
                                                       const unsigned short* __restrict__ Bt, int M,
                                                       const float* __restrict__ bias,
                                                       const float* __restrict__ Wl4, const float* __restrict__ Wr4,
                                                       const float* __restrict__ b4,
                                                       float* __restrict__ p, float* __restrict__ q) {
    __shared__ unsigned short As[128 * LP];
    __shared__ unsigned short Bs[128 * LP];
    __shared__ float psA[2][128], qsA[2][128];
    int tid = threadIdx.x;
    int m0 = blockIdx.x * 128;

    int lane = tid & 63;
    int wave = tid >> 6;
    int wm = (wave & 1) * 64;
    int wn = (wave >> 1) * 64;
    int lm = lane & 15;
    int lk = (lane >> 4) * 8;

    float4v acc[4][4];
    #pragma unroll
    for (int i = 0; i < 4; i++)
        #pragma unroll
        for (int j = 0; j < 4; j++) acc[i][j] = (float4v)0.f;

    int sr = tid >> 3;
    int sc = (tid & 7) * 8;

    for (int ks = 0; ks < lda; ks += 64) {
        if (ks) __syncthreads();
        int kk = ks + sc;
        #pragma unroll
        for (int rr = 0; rr < 128; rr += 32) {
            int r = sr + rr;
            int gm = m0 + r; if (gm > M - 1) gm = M - 1;
            *(ulonglong2*)&As[r * LP + sc] = *(const ulonglong2*)(A + (size_t)gm * lda + kk);
            *(ulonglong2*)&Bs[r * LP + sc] = *(const ulonglong2*)(Bt + (size_t)r * lda + kk);
        }
        __syncthreads();

        #pragma unroll
        for (int k0 = 0; k0 < 64; k0 += 32) {
            short8v af[4], bf[4];
            #pragma unroll
            for (int i = 0; i < 4; i++)
                af[i] = *(const short8v*)&As[(wm + i * 16 + lm) * LP + k0 + lk];
            #pragma unroll
            for (int j = 0; j < 4; j++)
                bf[j] = *(const short8v*)&Bs[(wn + j * 16 + lm) * LP + k0 + lk];
            #pragma unroll
            for (int i = 0; i < 4; i++)
                #pragma unroll
                for (int j = 0; j < 4; j++)
                    acc[i][j] = __builtin_amdgcn_mfma_f32_16x16x32_bf16(af[i], bf[j], acc[i][j], 0, 0, 0);
        }
    }

    int qd = lane >> 4;
    int wnidx = wave >> 1;
    float b3v[4], wlv[4], wrv[4];
    #pragma unroll
    for (int j = 0; j < 4; j++) {
        int cc = wn + j * 16 + lm;
        b3v[j] = bias[cc]; wlv[j] = Wl4[cc]; wrv[j] = Wr4[cc];
    }
    #pragma unroll
    for (int i = 0; i < 4; i++) {
        #pragma unroll
        for (int r = 0; r < 4; r++) {
            float pp = 0.f, qq = 0.f;
            #pragma unroll
            for (int j = 0; j < 4; j++) {
                float hv = fmaxf(acc[i][j][r] + b3v[j], 0.f);
                pp += hv * wlv[j]; qq += hv * wrv[j];
            }
            #pragma unroll
            for (int off = 1; off < 16; off <<= 1) {
                pp += __shfl_xor(pp, off);
                qq += __shfl_xor(qq, off);
            }
            if (lm == 0) {
                int m = wm + i * 16 + qd * 4 + r;
                psA[wnidx][m] = pp;
                qsA[wnidx][m] = qq;
            }
        }
    }
    __syncthreads();
    if (wnidx == 0 && lm == 0) {
        float b4v = b4[0];
        #pragma unroll
        for (int i = 0; i < 4; i++) {
            #pragma unroll
            for (int r = 0; r < 4; r++) {
                int m = wm + i * 16 + qd * 4 + r;
                int gm = m0 + m;
                if (gm < M) {
                    p[gm] = psA[0][m] + psA[1][m];
                    q[gm] = qsA[0][m] + qsA[1][m] + b4v;
                }
            }
        }
    }
}

__global__ __launch_bounds__(256) void final_kernel(const float* __restrict__ p, const float* __restrict__ q,
                                                    const int* __restrict__ row_ptr, const int* __restrict__ col,
                                                    const int* __restrict__ ord, float* __restrict__ out) {
    int i = blockIdx.x * 256 + threadIdx.x;   // sorted slot
    if (i >= N_NODES) return;
    int s = row_ptr[i], e = row_ptr[i + 1];
    float acc = 0.f;
    int t = s;
    for (; t + 3 < e; t += 4)
        acc += p[col[t]] + p[col[t + 1]] + p[col[t + 2]] + p[col[t + 3]];
    for (; t < e; t++) acc += p[col[t]];
    float di = 1.0f / fmaxf((float)(e - s), 1.0f);
    out[ord[i]] = acc * di + q[i];
}

// ---------------- launch ----------------

extern "C" void kernel_launch(void* const* d_in, const int* in_sizes, int n_in,
                              void* d_out, int out_size, void* d_ws, size_t ws_size,
                              hipStream_t stream) {
    const float* x    = (const float*)d_in[0];
    const int*   ei   = (const int*)d_in[1];
    const float* Wl1  = (const float*)d_in[2];
    const float* Wr1  = (const float*)d_in[3];
    const float* b1   = (const float*)d_in[4];
    const float* ln_g = (const float*)d_in[5];
    const float* ln_b = (const float*)d_in[6];
    const float* Wres = (const float*)d_in[7];
    const float* bres = (const float*)d_in[8];
    const float* Wl2  = (const float*)d_in[9];
    const float* Wr2  = (const float*)d_in[10];
    const float* b2   = (const float*)d_in[11];
    const float* Wl3  = (const float*)d_in[12];
    const float* Wr3  = (const float*)d_in[13];
    const float* b3   = (const float*)d_in[14];
    const float* Wl4  = (const float*)d_in[15];
    const float* Wr4  = (const float*)d_in[16];
    const float* b4   = (const float*)d_in[17];
    float* out = (float*)d_out;

    char* w = (char*)d_ws;
    size_t off = 0;
    auto alloc = [&](size_t bytes) -> void* {
        off = (off + 255) & ~(size_t)255;
        void* pp = w + off;
        off += bytes;
        return pp;
    };

    int*   deg        = (int*)alloc(N_NODES * 4);
    int*   deg_s      = (int*)alloc(N_NODES * 4);
    int*   row_ptr    = (int*)alloc((N_NODES + 1) * 4);
    int*   bsum       = (int*)alloc(512);
    int*   col        = (int*)alloc(N_EDGES * 4);
    int*   bucket_off = (int*)alloc((NBKT + 1) * 4);
    int*   bh2        = (int*)alloc(BH2_N * 4);
    int*   bh         = (int*)alloc(64 * SORT_BLOCKS * 4);
    int*   ord        = (int*)alloc(N_NODES * 4);
    int*   rank       = (int*)alloc(N_NODES * 4);
    unsigned short* Btw  = (unsigned short*)alloc(128 * 256 * 2);
    unsigned short* xcat = (unsigned short*)alloc((size_t)N_NODES * 128 * 2);  // [x | aggx] bf16
    unsigned short* hcat = (unsigned short*)alloc((size_t)N_NODES * 256 * 2);  // [h | aggh] bf16
    int*   packed  = (int*)alloc((size_t)N_EDGES * 4);   // CSR build scratch
    float* p       = (float*)alloc(N_NODES * 4);
    float* q       = (float*)alloc(N_NODES * 4);
    (void)ws_size; (void)n_in; (void)in_sizes; (void)out_size;

    const int NB = (N_NODES + 255) / 256;
    const int SCB = (N_NODES + 1023) / 1024;            // 98
    const int BHB = (BH2_N + 1023) / 1024;              // 92
    const int MB = (N_NODES + 127) / 128;               // 782

    // --- CSR build: hist -> scan -> scatter(packed) -> deg; degree sort; row_ptr; fill ---
    bkt_hist_kernel<<<SCAT_BLOCKS, 256, 0, stream>>>(ei, bh2);
    gscan_a_kernel<<<BHB, 256, 0, stream>>>(bh2, bsum, BH2_N);
    scan_b_kernel<<<1, 64, 0, stream>>>(bsum, BHB);
    gscan_c_kernel<<<BHB, 256, 0, stream>>>(bh2, bsum, BH2_N);
    extract_off_kernel<<<(NBKT + 256) / 256, 256, 0, stream>>>(bh2, bucket_off);
    bkt_scatter2_kernel<<<SCAT_BLOCKS, 256, 0, stream>>>(ei, bh2, packed);
    bkt_deg2_kernel<<<NBKT, 256, 0, stream>>>(packed, bucket_off, deg);
    dsort_hist_kernel<<<SORT_BLOCKS, 256, 0, stream>>>(deg, bh);
    dsort_scan_kernel<<<1, 256, 0, stream>>>(bh);
    dsort_scat_kernel<<<SORT_BLOCKS, 256, 0, stream>>>(deg, bh, ord, rank, deg_s);
    gscan_a_kernel<<<SCB, 256, 0, stream>>>(deg_s, bsum, N_NODES);
    scan_b_kernel<<<1, 128, 0, stream>>>(bsum, SCB);
    scan_c_row_kernel<<<SCB, 256, 0, stream>>>(deg_s, bsum, row_ptr);
    bkt_fill2_kernel<<<NBKT, 256, 0, stream>>>(packed, bucket_off, row_ptr, rank, col);

    // --- layer 1: xcat = [x | mean-agg(x)]; fused GEMM+LN -> hcat[:,0:128] ---
    xbf_kernel<<<(N_NODES * 16 + 255) / 256, 256, 0, stream>>>(x, rank, xcat);
    agg64_kernel<<<(N_NODES + 15) / 16, 256, 0, stream>>>(xcat, row_ptr, col);
    wprep1_kernel<<<128, 256, 0, stream>>>(Wr1, Wl1, Wres, Btw);
    mgemm1_ln_kernel<<<MB, 256, 0, stream>>>(xcat, Btw, N_NODES, b1, ln_g, ln_b, bres, hcat);

    // --- layer 2: agg(h) -> hcat[:,128:256]; GEMM [h|aggh] -> hcat[:,0:128] (bias+relu) ---
    agg128_kernel<<<(N_NODES + 7) / 8, 256, 0, stream>>>(hcat, row_ptr, col);
    wprep23_kernel<<<128, 256, 0, stream>>>(Wl2, Wr2, Btw);
    mgemm_kernel<<<dim3(MB, 1), 256, 0, stream>>>(hcat, 256, Btw, N_NODES, b2, hcat, 256);

    // --- layer 3: agg(h) -> hcat[:,128:256]; fused GEMM+pq -> p, q (h3 never stored) ---
    agg128_kernel<<<(N_NODES + 7) / 8, 256, 0, stream>>>(hcat, row_ptr, col);
    wprep23_kernel<<<128, 256, 0, stream>>>(Wl3, Wr3, Btw);
    mgemm_pq_kernel<<<MB, 256, 0, stream>>>(hcat, 256, Btw, N_NODES, b3, Wl4, Wr4, b4, p, q);

    // --- final ---
    final_kernel<<<NB, 256, 0, stream>>>(p, q, row_ptr, col, ord, out);
}